// Round 4
// baseline (77.173 us; speedup 1.0000x reference)
//
#include <hip/hip_runtime.h>

#define BB 4
#define NN 16384
#define SS 2048
#define CC 64
#define NS 32
#define KK 33   // NS + 1 (fps_idx prepended)
#define OC 70   // 3 raw xyz + 3 centered xyz + 64 features
#define SCH 4   // s-chunk per main block
#define GT 512  // gather/main block threads
#define NC 10
#define NCELL 1000
#define HCAP 224         // per-wave hit buffer cap (avg hits ~62)
#define RPAD 0.100001f   // cell-range pad (covers fp rounding of d2 test)

// --- prevent fma contraction so d2 matches the np/jax fp32 reference ---
__device__ __forceinline__ float sq_nofma(float v) {
  float r = v * v;
  asm volatile("" : "+v"(r));
  return r;
}

__device__ __forceinline__ int cell1(float x) {
  int c = (int)(x * 10.0f);
  return c < 0 ? 0 : (c > 9 ? 9 : c);
}
__device__ __forceinline__ int cell3(float x, float y, float z) {
  return (cell1(z) * NC + cell1(y)) * NC + cell1(x);
}

// ---------------- legacy wave ball-query (fallback + overflow path) -------
__device__ __forceinline__ void ball_query_wave(
    const float* __restrict__ xb, float qx, float qy, float qz, int lane,
    int* out) {
  const float R2 = 0.01f;
  int cnt = 0;
  int firstIdx = 0;
  for (int base = 0; base < NN; base += 256) {
    float px[4], py[4], pz[4];
#pragma unroll
    for (int j = 0; j < 4; ++j) {
      int n = base + j * 64 + lane;
      const float* p = xb + n * 3;
      px[j] = p[0]; py[j] = p[1]; pz[j] = p[2];
    }
#pragma unroll
    for (int j = 0; j < 4; ++j) {
      float dx = px[j] - qx, dy = py[j] - qy, dz = pz[j] - qz;
      float d2 = sq_nofma(dx) + sq_nofma(dy);
      asm volatile("" : "+v"(d2));
      d2 = d2 + sq_nofma(dz);
      bool m = d2 < R2;
      unsigned long long bal = __ballot(m);
      if (cnt == 0 && bal) firstIdx = base + j * 64 + __builtin_ctzll(bal);
      int pos = cnt + (int)__popcll(bal & ((1ull << lane) - 1ull));
      if (m && pos < NS) out[pos] = base + j * 64 + lane;
      cnt += (int)__popcll(bal);
    }
    if (cnt >= NS) break;
  }
  if (cnt < NS) {
    int pad = (cnt == 0) ? 0 : firstIdx;
    if (lane >= cnt && lane < NS) out[lane] = pad;
  }
}

// ---------------- K1: per-batch grid build+scatter (4 blocks) + transpose --
__global__ __launch_bounds__(256) void qg_prep3(
    const float* __restrict__ xyz, const float* __restrict__ feat,
    int* __restrict__ off, float4* __restrict__ pts,
    float* __restrict__ featT) {
  __shared__ float tile[64][65];
  __shared__ int h[1024];
  __shared__ int sc[256];
  const int bid = (int)blockIdx.x;
  const int tid = (int)threadIdx.x;
  if (bid < BB) {
    // ---- build histogram + scan + scatter for batch `bid`, block-local ----
    const int b = bid;
    const float* xb = xyz + (size_t)b * NN * 3;
    for (int c = tid; c < 1024; c += 256) h[c] = 0;
    __syncthreads();
    for (int i = tid; i < NN; i += 256) {
      const float* p = xb + 3 * i;
      atomicAdd(&h[cell3(p[0], p[1], p[2])], 1);
    }
    __syncthreads();
    int base = tid * 4;
    int l0 = h[base], l1 = h[base + 1], l2 = h[base + 2], l3 = h[base + 3];
    int s1 = l0, s2 = l0 + l1, s3 = l0 + l1 + l2, tot = s3 + l3;
    sc[tid] = tot;
    __syncthreads();
    for (int d = 1; d < 256; d <<= 1) {
      int v = (tid >= d) ? sc[tid - d] : 0;
      __syncthreads();
      sc[tid] += v;
      __syncthreads();
    }
    int ex = sc[tid] - tot;
    int* offb = off + b * (NCELL + 1);
    // publish offsets to global (for K2) and rewrite h as running counters
    if (base + 0 < NCELL) offb[base + 0] = ex;
    if (base + 1 < NCELL) offb[base + 1] = ex + s1;
    if (base + 2 < NCELL) offb[base + 2] = ex + s2;
    if (base + 3 < NCELL) offb[base + 3] = ex + s3;
    if (tid == 0) offb[NCELL] = NN;
    h[base + 0] = ex;
    h[base + 1] = ex + s1;
    h[base + 2] = ex + s2;
    h[base + 3] = ex + s3;
    __syncthreads();
    // scatter pass (in-cell order nondeterministic; final output rank-sorted)
    float4* pb = pts + ((size_t)b << 14);
    for (int i = tid; i < NN; i += 256) {
      const float* p = xb + 3 * i;
      float x = p[0], y = p[1], z = p[2];
      int pos = atomicAdd(&h[cell3(x, y, z)], 1);
      pb[pos] = make_float4(x, y, z, __int_as_float(i));
    }
  } else {
    // ---- feature transpose: 64c x 64n tile ----
    int tb = bid - BB;          // 0..1023
    int b = tb >> 8;
    int n0 = (tb & 255) << 6;
    int tx = tid & 63;
    int ty = tid >> 6;  // 0..3
    const float* fb = feat + (size_t)b * CC * NN + n0;
#pragma unroll
    for (int r = 0; r < 16; ++r) {
      int c = r * 4 + ty;
      tile[c][tx] = fb[(size_t)c * NN + tx];
    }
    __syncthreads();
    float* ob = featT + ((size_t)b * NN + n0) * CC;
#pragma unroll
    for (int r = 0; r < 16; ++r) {
      int n = r * 4 + ty;
      ob[(size_t)n * CC + tx] = tile[tx][n];
    }
  }
}

// ---------------- K2: fused grid ball-query + gather ----------------------
// Block = (b, 4 consecutive s). Waves 0..3 run the 4 ball queries (results in
// LDS); then all 512 threads gather featT/xyz and write the output tile.
__global__ __launch_bounds__(GT) void qg_main(
    const float* __restrict__ xyz, const float* __restrict__ nxyz,
    const float4* __restrict__ pts, const int* __restrict__ off,
    const float* __restrict__ featT, const int* __restrict__ fps,
    float* __restrict__ out) {
  __shared__ float sf[CC][SCH * KK + 1];  // [64][133]
  __shared__ int sidx[SCH * KK];          // 132
  __shared__ int hitbuf[SCH][HCAP];
  __shared__ int hcnt_s[SCH];
  const int tid = (int)threadIdx.x;
  const int blk = (int)blockIdx.x;  // 0..2047
  const int b = blk >> 9;
  const int s0 = (blk & 511) * SCH;
  const int wv = tid >> 6, lane = tid & 63;

  // ---- phase 1: ball query (waves 0..3, one query each) ----
  if (wv < SCH) {
    const int q = b * SS + s0 + wv;
    const float R2 = 0.01f;
    float qx = nxyz[q * 3 + 0];
    float qy = nxyz[q * 3 + 1];
    float qz = nxyz[q * 3 + 2];
    int* hb = hitbuf[wv];
    int* qout = &sidx[wv * KK];
    if (lane == 0) hcnt_s[wv] = 0;
    asm volatile("s_waitcnt lgkmcnt(0)" ::: "memory");

    int lox = max(0, (int)floorf((qx - RPAD) * 10.f));
    int hix = min(9, (int)floorf((qx + RPAD) * 10.f));
    int loy = max(0, (int)floorf((qy - RPAD) * 10.f));
    int hiy = min(9, (int)floorf((qy + RPAD) * 10.f));
    int loz = max(0, (int)floorf((qz - RPAD) * 10.f));
    int hiz = min(9, (int)floorf((qz + RPAD) * 10.f));

    // hoist span bounds: lane i in [0,9) owns span (loz+i/3, loy+i%3)
    const int* offb = off + b * (NCELL + 1);
    int start_l = 0, end_l = 0;
    {
      int cz = loz + lane / 3, cy = loy + lane % 3;
      if (lane < 9 && cz <= hiz && cy <= hiy) {
        int row = (cz * NC + cy) * NC;
        start_l = offb[row + lox];
        end_l = offb[row + hix + 1];
      }
    }
    const float4* pb = pts + ((size_t)b << 14);
    // dependence-free candidate loop: loads pipeline, no per-iter ballot
    for (int sp = 0; sp < 9; ++sp) {
      int start = __shfl(start_l, sp, 64);
      int end = __shfl(end_l, sp, 64);
      for (int p0 = start; p0 < end; p0 += 64) {
        int ii = p0 + lane;
        bool valid = ii < end;
        float4 v = pb[valid ? ii : (end - 1)];
        float dx = v.x - qx, dy = v.y - qy, dz = v.z - qz;
        float d2 = sq_nofma(dx) + sq_nofma(dy);
        asm volatile("" : "+v"(d2));
        d2 = d2 + sq_nofma(dz);
        if (valid && d2 < R2) {
          int pos = atomicAdd(&hcnt_s[wv], 1);
          if (pos < HCAP) hb[pos] = __float_as_int(v.w);
        }
      }
    }
    asm volatile("s_waitcnt lgkmcnt(0)" ::: "memory");
    const int M = hcnt_s[wv];
    if (M > HCAP) {
      // safety net: exact legacy linear scan (prob ~0 on this data)
      ball_query_wave(xyz + (size_t)b * NN * 3, qx, qy, qz, lane, qout + 1);
    } else {
      // rank by original index = output position (order-independent)
      int minv = 0x7fffffff;
      for (int i = lane; i < M; i += 64) {
        int hh = hb[i];
        minv = min(minv, hh);
        int rank = 0;
        for (int j = 0; j < M; ++j) rank += (hb[j] < hh) ? 1 : 0;
        if (rank < NS) qout[1 + rank] = hh;
      }
      if (M < NS) {
#pragma unroll
        for (int d = 1; d < 64; d <<= 1)
          minv = min(minv, __shfl_xor(minv, d, 64));
        int pad = (M == 0) ? 0 : minv;
        if (lane >= M && lane < NS) qout[1 + lane] = pad;
      }
    }
    if (lane == 0) qout[0] = fps[q];
  }
  __syncthreads();

  // ---- phase 2: gather (all 512 threads) ----
  const size_t cstr = (size_t)SS * KK;
  const float4* fT4 = (const float4*)(featT + (size_t)b * NN * CC);
  int e = tid & 15;
  for (int pp = tid >> 4; pp < SCH * KK; pp += GT / 16) {
    int n = sidx[pp];
    float4 v = fT4[(size_t)n * (CC / 4) + e];
    sf[4 * e + 0][pp] = v.x;
    sf[4 * e + 1][pp] = v.y;
    sf[4 * e + 2][pp] = v.z;
    sf[4 * e + 3][pp] = v.w;
  }

  if (tid < SCH * KK) {
    int s4 = tid / KK;
    int n = sidx[tid];
    const float* p = xyz + ((size_t)b * NN + n) * 3;
    float x = p[0], y = p[1], z = p[2];
    int q = b * SS + s0 + s4;
    float cx = nxyz[q * 3 + 0], cy = nxyz[q * 3 + 1], cz = nxyz[q * 3 + 2];
    size_t obase = ((size_t)(b * OC) * SS + s0) * KK + tid;
    out[obase + 0 * cstr] = x;
    out[obase + 1 * cstr] = y;
    out[obase + 2 * cstr] = z;
    out[obase + 3 * cstr] = x - cx;
    out[obase + 4 * cstr] = y - cy;
    out[obase + 5 * cstr] = z - cz;
  }
  __syncthreads();

  size_t fbase = ((size_t)(b * OC + 6) * SS + s0) * KK;
  for (int idx = tid; idx < CC * SCH * KK; idx += GT) {
    int c = idx / (SCH * KK);
    int j = idx - c * (SCH * KK);
    out[fbase + (size_t)c * cstr + j] = sf[c][j];
  }
}

// ---------------- legacy fallback kernels (small-ws paths) ----------------
__global__ __launch_bounds__(256) void qg_prep(
    const float* __restrict__ xyz, const float* __restrict__ nxyz,
    const float* __restrict__ feat, int* __restrict__ wsidx,
    float* __restrict__ featT) {
  __shared__ float tile[64][65];
  int bid = (int)blockIdx.x;
  int r3 = bid % 3;
  if (r3 < 2) {
    int lane = (int)(threadIdx.x & 63);
    int q = ((bid / 3) * 2 + r3) * 4 + (int)(threadIdx.x >> 6);
    int b = q >> 11;
    const float* xb = xyz + (size_t)b * NN * 3;
    ball_query_wave(xb, nxyz[q * 3], nxyz[q * 3 + 1], nxyz[q * 3 + 2], lane,
                    wsidx + (size_t)q * NS);
  } else {
    int tb = bid / 3;
    int b = tb >> 8;
    int n0 = (tb & 255) << 6;
    int tx = (int)(threadIdx.x & 63);
    int ty = (int)(threadIdx.x >> 6);
    const float* fb = feat + (size_t)b * CC * NN + n0;
#pragma unroll
    for (int r = 0; r < 16; ++r) {
      int c = r * 4 + ty;
      tile[c][tx] = fb[(size_t)c * NN + tx];
    }
    __syncthreads();
    float* ob = featT + ((size_t)b * NN + n0) * CC;
#pragma unroll
    for (int r = 0; r < 16; ++r) {
      int n = r * 4 + ty;
      ob[(size_t)n * CC + tx] = tile[tx][n];
    }
  }
}

__global__ __launch_bounds__(GT) void qg_gather2(
    const float* __restrict__ xyz, const float* __restrict__ nxyz,
    const float* __restrict__ featT, const int* __restrict__ fps,
    const int* __restrict__ wsidx, float* __restrict__ out) {
  __shared__ float sf[CC][SCH * KK + 1];
  __shared__ int sidx[SCH * KK];
  const int tid = (int)threadIdx.x;
  const int blk = (int)blockIdx.x;
  const int b = blk >> 9;
  const int s0 = (blk & 511) * SCH;
  const size_t cstr = (size_t)SS * KK;

  if (tid < SCH * KK) {
    int s4 = tid / KK, k = tid - s4 * KK;
    int q = b * SS + s0 + s4;
    sidx[tid] = (k == 0) ? fps[q] : wsidx[(size_t)q * NS + (k - 1)];
  }
  __syncthreads();

  const float4* fT4 = (const float4*)(featT + (size_t)b * NN * CC);
  int e = tid & 15;
  for (int pp = tid >> 4; pp < SCH * KK; pp += GT / 16) {
    int n = sidx[pp];
    float4 v = fT4[(size_t)n * (CC / 4) + e];
    sf[4 * e + 0][pp] = v.x;
    sf[4 * e + 1][pp] = v.y;
    sf[4 * e + 2][pp] = v.z;
    sf[4 * e + 3][pp] = v.w;
  }

  if (tid < SCH * KK) {
    int s4 = tid / KK;
    int n = sidx[tid];
    const float* p = xyz + ((size_t)b * NN + n) * 3;
    float x = p[0], y = p[1], z = p[2];
    int q = b * SS + s0 + s4;
    float cx = nxyz[q * 3 + 0], cy = nxyz[q * 3 + 1], cz = nxyz[q * 3 + 2];
    size_t obase = ((size_t)(b * OC) * SS + s0) * KK + tid;
    out[obase + 0 * cstr] = x;
    out[obase + 1 * cstr] = y;
    out[obase + 2 * cstr] = z;
    out[obase + 3 * cstr] = x - cx;
    out[obase + 4 * cstr] = y - cy;
    out[obase + 5 * cstr] = z - cz;
  }
  __syncthreads();

  size_t fbase = ((size_t)(b * OC + 6) * SS + s0) * KK;
  for (int idx = tid; idx < CC * SCH * KK; idx += GT) {
    int c = idx / (SCH * KK);
    int j = idx - c * (SCH * KK);
    out[fbase + (size_t)c * cstr + j] = sf[c][j];
  }
}

__global__ __launch_bounds__(256) void qg_ballq(
    const float* __restrict__ xyz, const float* __restrict__ nxyz,
    int* __restrict__ wsidx) {
  int q = (int)((blockIdx.x * blockDim.x + threadIdx.x) >> 6);
  int lane = (int)(threadIdx.x & 63);
  int b = q / SS;
  const float* xb = xyz + (size_t)b * NN * 3;
  ball_query_wave(xb, nxyz[q * 3], nxyz[q * 3 + 1], nxyz[q * 3 + 2], lane,
                  wsidx + (size_t)q * NS);
}

__global__ __launch_bounds__(256) void qg_gather(
    const float* __restrict__ xyz, const float* __restrict__ nxyz,
    const float* __restrict__ feat, const int* __restrict__ fps,
    const int* __restrict__ wsidx, float* __restrict__ out) {
  unsigned t = blockIdx.x * 256u + threadIdx.x;
  const unsigned TOT = (unsigned)BB * OC * SS * KK;
  if (t >= TOT) return;
  unsigned k = t % KK;
  unsigned r = t / KK;
  unsigned s = r % SS;
  r /= SS;
  unsigned c = r % OC;
  unsigned b = r / OC;
  unsigned q = b * SS + s;
  int n = (k == 0) ? fps[q] : wsidx[(size_t)q * NS + (k - 1)];
  float v;
  if (c < 6) {
    unsigned cc = (c < 3) ? c : c - 3;
    v = xyz[((size_t)b * NN + (unsigned)n) * 3 + cc];
    if (c >= 3) v -= nxyz[q * 3 + cc];
  } else {
    v = feat[((size_t)b * CC + (c - 6)) * NN + (unsigned)n];
  }
  out[t] = v;
}

__global__ __launch_bounds__(256) void qg_fused(
    const float* __restrict__ xyz, const float* __restrict__ nxyz,
    const float* __restrict__ feat, const int* __restrict__ fps,
    float* __restrict__ out) {
  __shared__ int sidx[4][KK];
  int wv = (int)(threadIdx.x >> 6), lane = (int)(threadIdx.x & 63);
  int q = (int)blockIdx.x * 4 + wv;
  int b = q / SS, s = q % SS;
  const float* xb = xyz + (size_t)b * NN * 3;
  ball_query_wave(xb, nxyz[q * 3], nxyz[q * 3 + 1], nxyz[q * 3 + 2], lane,
                  &sidx[wv][1]);
  if (lane == 0) sidx[wv][0] = fps[q];
  __syncthreads();
  for (int f = lane; f < OC * KK; f += 64) {
    int c = f / KK, k = f - c * KK;
    int n = sidx[wv][k];
    float v;
    if (c < 6) {
      int cc = (c < 3) ? c : c - 3;
      v = xb[n * 3 + cc];
      if (c >= 3) v -= nxyz[q * 3 + cc];
    } else {
      v = feat[((size_t)b * CC + (c - 6)) * NN + n];
    }
    out[((size_t)((size_t)b * OC + c) * SS + s) * KK + k] = v;
  }
}

extern "C" void kernel_launch(void* const* d_in, const int* in_sizes, int n_in,
                              void* d_out, int out_size, void* d_ws, size_t ws_size,
                              hipStream_t stream) {
  const float* xyz  = (const float*)d_in[0];   // (B, N, 3)
  const float* nxyz = (const float*)d_in[1];   // (B, S, 3)
  const float* feat = (const float*)d_in[2];   // (B, C, N)
  const int*   fps  = (const int*)d_in[3];     // (B, S)
  float* out = (float*)d_out;                  // (B, 70, S, 33)

  const size_t idx_b   = (size_t)BB * SS * NS * sizeof(int);     // 1 MiB
  const size_t pts_b   = (size_t)BB * NN * sizeof(float4);       // 1 MiB
  const size_t off_b   = 16384;
  const size_t woff_b  = 16384;                                  // reserved
  const size_t featT_b = (size_t)BB * NN * CC * sizeof(float);   // 16.8 MB
  const size_t grid_need = idx_b + pts_b + off_b + woff_b + featT_b;

  if (ws_size >= grid_need) {
    char* w = (char*)d_ws;
    /* wsidx (unused in main path) */                w += idx_b;
    float4* pts   = (float4*)w;                      w += pts_b;
    int*    off   = (int*)w;                         w += off_b;
    /* woff reserved */                              w += woff_b;
    float*  featT = (float*)w;
    qg_prep3<<<BB + 1024, 256, 0, stream>>>(xyz, feat, off, pts, featT);
    qg_main<<<BB * (SS / SCH), GT, 0, stream>>>(xyz, nxyz, pts, off, featT,
                                                fps, out);
  } else if (ws_size >= idx_b + featT_b) {
    int* wsidx = (int*)d_ws;
    float* featT = (float*)((char*)d_ws + idx_b);
    qg_prep<<<3072, 256, 0, stream>>>(xyz, nxyz, feat, wsidx, featT);
    qg_gather2<<<BB * (SS / SCH), GT, 0, stream>>>(xyz, nxyz, featT, fps,
                                                   wsidx, out);
  } else if (ws_size >= idx_b) {
    int* wsidx = (int*)d_ws;
    qg_ballq<<<(BB * SS) / 4, 256, 0, stream>>>(xyz, nxyz, wsidx);
    unsigned tot = (unsigned)BB * OC * SS * KK;
    qg_gather<<<(tot + 255u) / 256u, 256, 0, stream>>>(xyz, nxyz, feat, fps,
                                                       wsidx, out);
  } else {
    qg_fused<<<(BB * SS) / 4, 256, 0, stream>>>(xyz, nxyz, feat, fps, out);
  }
}

// Round 5
// 65.776 us; speedup vs baseline: 1.1733x; 1.1733x over previous
//
#include <hip/hip_runtime.h>

#define BB 4
#define NN 16384
#define SS 2048
#define CC 64
#define NS 32
#define KK 33   // NS + 1 (fps_idx prepended)
#define OC 70   // 3 raw xyz + 3 centered xyz + 64 features
#define SCH 4   // s-chunk per main block
#define GT 512  // gather/main block threads
#define NC 10
#define NCELL 1000
#define HCAP 224         // per-wave hit buffer cap (avg hits ~62)
#define RPAD 0.100001f   // cell-range pad (covers fp rounding of d2 test)

// --- prevent fma contraction so d2 matches the np/jax fp32 reference ---
__device__ __forceinline__ float sq_nofma(float v) {
  float r = v * v;
  asm volatile("" : "+v"(r));
  return r;
}

__device__ __forceinline__ int cell1(float x) {
  int c = (int)(x * 10.0f);
  return c < 0 ? 0 : (c > 9 ? 9 : c);
}
__device__ __forceinline__ int cell3(float x, float y, float z) {
  return (cell1(z) * NC + cell1(y)) * NC + cell1(x);
}

// ---------------- legacy wave ball-query (fallback + overflow path) -------
__device__ __forceinline__ void ball_query_wave(
    const float* __restrict__ xb, float qx, float qy, float qz, int lane,
    int* out) {
  const float R2 = 0.01f;
  int cnt = 0;
  int firstIdx = 0;
  for (int base = 0; base < NN; base += 256) {
    float px[4], py[4], pz[4];
#pragma unroll
    for (int j = 0; j < 4; ++j) {
      int n = base + j * 64 + lane;
      const float* p = xb + n * 3;
      px[j] = p[0]; py[j] = p[1]; pz[j] = p[2];
    }
#pragma unroll
    for (int j = 0; j < 4; ++j) {
      float dx = px[j] - qx, dy = py[j] - qy, dz = pz[j] - qz;
      float d2 = sq_nofma(dx) + sq_nofma(dy);
      asm volatile("" : "+v"(d2));
      d2 = d2 + sq_nofma(dz);
      bool m = d2 < R2;
      unsigned long long bal = __ballot(m);
      if (cnt == 0 && bal) firstIdx = base + j * 64 + __builtin_ctzll(bal);
      int pos = cnt + (int)__popcll(bal & ((1ull << lane) - 1ull));
      if (m && pos < NS) out[pos] = base + j * 64 + lane;
      cnt += (int)__popcll(bal);
    }
    if (cnt >= NS) break;
  }
  if (cnt < NS) {
    int pad = (cnt == 0) ? 0 : firstIdx;
    if (lane >= cnt && lane < NS) out[lane] = pad;
  }
}

// ---------------- K1: grid build (4 blocks) + feature transpose -----------
// (verified in R3 bench) — hist+scan blocks hide under the transpose stream.
__global__ __launch_bounds__(256) void qg_build_tr(
    const float* __restrict__ xyz, const float* __restrict__ feat,
    int* __restrict__ off, int* __restrict__ woff, float* __restrict__ featT) {
  __shared__ float tile[64][65];
  __shared__ int h[1024];
  __shared__ int sc[256];
  const int bid = (int)blockIdx.x;
  const int tid = (int)threadIdx.x;
  if (bid < BB) {
    const int b = bid;
    const float* xb = xyz + (size_t)b * NN * 3;
    for (int c = tid; c < 1024; c += 256) h[c] = 0;
    __syncthreads();
    for (int i = tid; i < NN; i += 256) {
      const float* p = xb + 3 * i;
      atomicAdd(&h[cell3(p[0], p[1], p[2])], 1);
    }
    __syncthreads();
    int base = tid * 4;
    int l0 = h[base], l1 = h[base + 1], l2 = h[base + 2], l3 = h[base + 3];
    int s1 = l0, s2 = l0 + l1, s3 = l0 + l1 + l2, tot = s3 + l3;
    sc[tid] = tot;
    __syncthreads();
    for (int d = 1; d < 256; d <<= 1) {
      int v = (tid >= d) ? sc[tid - d] : 0;
      __syncthreads();
      sc[tid] += v;
      __syncthreads();
    }
    int ex = sc[tid] - tot;
    int* offb = off + b * (NCELL + 1);
    int* woffb = woff + b * NCELL;
    if (base + 0 < NCELL) { offb[base + 0] = ex;      woffb[base + 0] = ex; }
    if (base + 1 < NCELL) { offb[base + 1] = ex + s1; woffb[base + 1] = ex + s1; }
    if (base + 2 < NCELL) { offb[base + 2] = ex + s2; woffb[base + 2] = ex + s2; }
    if (base + 3 < NCELL) { offb[base + 3] = ex + s3; woffb[base + 3] = ex + s3; }
    if (tid == 0) offb[NCELL] = NN;
  } else {
    // ---- feature transpose: 64c x 64n tile ----
    int tb = bid - BB;          // 0..1023
    int b = tb >> 8;
    int n0 = (tb & 255) << 6;
    int tx = tid & 63;
    int ty = tid >> 6;  // 0..3
    const float* fb = feat + (size_t)b * CC * NN + n0;
#pragma unroll
    for (int r = 0; r < 16; ++r) {
      int c = r * 4 + ty;
      tile[c][tx] = fb[(size_t)c * NN + tx];
    }
    __syncthreads();
    float* ob = featT + ((size_t)b * NN + n0) * CC;
#pragma unroll
    for (int r = 0; r < 16; ++r) {
      int n = r * 4 + ty;
      ob[(size_t)n * CC + tx] = tile[tx][n];
    }
  }
}

// ---------------- K2: counting-sort scatter (256 blocks, verified R3) -----
__global__ __launch_bounds__(256) void qg_scatter(
    const float* __restrict__ xyz, int* __restrict__ woff,
    float4* __restrict__ pts) {
  int i = (int)(blockIdx.x * 256u + threadIdx.x);  // 0..65535
  int b = i >> 14, n = i & (NN - 1);
  const float* p = xyz + ((size_t)b * NN + n) * 3;
  float x = p[0], y = p[1], z = p[2];
  int cell = cell3(x, y, z);
  int pos = atomicAdd(&woff[b * NCELL + cell], 1);
  pts[(b << 14) + pos] = make_float4(x, y, z, __int_as_float(n));
}

// ---------------- K3: fused grid ball-query + gather (verified R4) --------
__global__ __launch_bounds__(GT) void qg_main(
    const float* __restrict__ xyz, const float* __restrict__ nxyz,
    const float4* __restrict__ pts, const int* __restrict__ off,
    const float* __restrict__ featT, const int* __restrict__ fps,
    float* __restrict__ out) {
  __shared__ float sf[CC][SCH * KK + 1];  // [64][133]
  __shared__ int sidx[SCH * KK];          // 132
  __shared__ int hitbuf[SCH][HCAP];
  __shared__ int hcnt_s[SCH];
  const int tid = (int)threadIdx.x;
  const int blk = (int)blockIdx.x;  // 0..2047
  const int b = blk >> 9;
  const int s0 = (blk & 511) * SCH;
  const int wv = tid >> 6, lane = tid & 63;

  // ---- phase 1: ball query (waves 0..3, one query each) ----
  if (wv < SCH) {
    const int q = b * SS + s0 + wv;
    const float R2 = 0.01f;
    float qx = nxyz[q * 3 + 0];
    float qy = nxyz[q * 3 + 1];
    float qz = nxyz[q * 3 + 2];
    int* hb = hitbuf[wv];
    int* qout = &sidx[wv * KK];
    if (lane == 0) hcnt_s[wv] = 0;
    asm volatile("s_waitcnt lgkmcnt(0)" ::: "memory");

    int lox = max(0, (int)floorf((qx - RPAD) * 10.f));
    int hix = min(9, (int)floorf((qx + RPAD) * 10.f));
    int loy = max(0, (int)floorf((qy - RPAD) * 10.f));
    int hiy = min(9, (int)floorf((qy + RPAD) * 10.f));
    int loz = max(0, (int)floorf((qz - RPAD) * 10.f));
    int hiz = min(9, (int)floorf((qz + RPAD) * 10.f));

    // hoist span bounds: lane i in [0,9) owns span (loz+i/3, loy+i%3)
    const int* offb = off + b * (NCELL + 1);
    int start_l = 0, end_l = 0;
    {
      int cz = loz + lane / 3, cy = loy + lane % 3;
      if (lane < 9 && cz <= hiz && cy <= hiy) {
        int row = (cz * NC + cy) * NC;
        start_l = offb[row + lox];
        end_l = offb[row + hix + 1];
      }
    }
    const float4* pb = pts + ((size_t)b << 14);
    // dependence-free candidate loop: loads pipeline, no per-iter ballot
    for (int sp = 0; sp < 9; ++sp) {
      int start = __shfl(start_l, sp, 64);
      int end = __shfl(end_l, sp, 64);
      for (int p0 = start; p0 < end; p0 += 64) {
        int ii = p0 + lane;
        bool valid = ii < end;
        float4 v = pb[valid ? ii : (end - 1)];
        float dx = v.x - qx, dy = v.y - qy, dz = v.z - qz;
        float d2 = sq_nofma(dx) + sq_nofma(dy);
        asm volatile("" : "+v"(d2));
        d2 = d2 + sq_nofma(dz);
        if (valid && d2 < R2) {
          int pos = atomicAdd(&hcnt_s[wv], 1);
          if (pos < HCAP) hb[pos] = __float_as_int(v.w);
        }
      }
    }
    asm volatile("s_waitcnt lgkmcnt(0)" ::: "memory");
    const int M = hcnt_s[wv];
    if (M > HCAP) {
      // safety net: exact legacy linear scan (prob ~0 on this data)
      ball_query_wave(xyz + (size_t)b * NN * 3, qx, qy, qz, lane, qout + 1);
    } else {
      // rank by original index = output position (order-independent)
      int minv = 0x7fffffff;
      for (int i = lane; i < M; i += 64) {
        int hh = hb[i];
        minv = min(minv, hh);
        int rank = 0;
        for (int j = 0; j < M; ++j) rank += (hb[j] < hh) ? 1 : 0;
        if (rank < NS) qout[1 + rank] = hh;
      }
      if (M < NS) {
#pragma unroll
        for (int d = 1; d < 64; d <<= 1)
          minv = min(minv, __shfl_xor(minv, d, 64));
        int pad = (M == 0) ? 0 : minv;
        if (lane >= M && lane < NS) qout[1 + lane] = pad;
      }
    }
    if (lane == 0) qout[0] = fps[q];
  }
  __syncthreads();

  // ---- phase 2: gather (all 512 threads) ----
  const size_t cstr = (size_t)SS * KK;
  const float4* fT4 = (const float4*)(featT + (size_t)b * NN * CC);
  int e = tid & 15;
  for (int pp = tid >> 4; pp < SCH * KK; pp += GT / 16) {
    int n = sidx[pp];
    float4 v = fT4[(size_t)n * (CC / 4) + e];
    sf[4 * e + 0][pp] = v.x;
    sf[4 * e + 1][pp] = v.y;
    sf[4 * e + 2][pp] = v.z;
    sf[4 * e + 3][pp] = v.w;
  }

  if (tid < SCH * KK) {
    int s4 = tid / KK;
    int n = sidx[tid];
    const float* p = xyz + ((size_t)b * NN + n) * 3;
    float x = p[0], y = p[1], z = p[2];
    int q = b * SS + s0 + s4;
    float cx = nxyz[q * 3 + 0], cy = nxyz[q * 3 + 1], cz = nxyz[q * 3 + 2];
    size_t obase = ((size_t)(b * OC) * SS + s0) * KK + tid;
    out[obase + 0 * cstr] = x;
    out[obase + 1 * cstr] = y;
    out[obase + 2 * cstr] = z;
    out[obase + 3 * cstr] = x - cx;
    out[obase + 4 * cstr] = y - cy;
    out[obase + 5 * cstr] = z - cz;
  }
  __syncthreads();

  size_t fbase = ((size_t)(b * OC + 6) * SS + s0) * KK;
  for (int idx = tid; idx < CC * SCH * KK; idx += GT) {
    int c = idx / (SCH * KK);
    int j = idx - c * (SCH * KK);
    out[fbase + (size_t)c * cstr + j] = sf[c][j];
  }
}

// ---------------- legacy fallback kernels (small-ws paths) ----------------
__global__ __launch_bounds__(256) void qg_prep(
    const float* __restrict__ xyz, const float* __restrict__ nxyz,
    const float* __restrict__ feat, int* __restrict__ wsidx,
    float* __restrict__ featT) {
  __shared__ float tile[64][65];
  int bid = (int)blockIdx.x;
  int r3 = bid % 3;
  if (r3 < 2) {
    int lane = (int)(threadIdx.x & 63);
    int q = ((bid / 3) * 2 + r3) * 4 + (int)(threadIdx.x >> 6);
    int b = q >> 11;
    const float* xb = xyz + (size_t)b * NN * 3;
    ball_query_wave(xb, nxyz[q * 3], nxyz[q * 3 + 1], nxyz[q * 3 + 2], lane,
                    wsidx + (size_t)q * NS);
  } else {
    int tb = bid / 3;
    int b = tb >> 8;
    int n0 = (tb & 255) << 6;
    int tx = (int)(threadIdx.x & 63);
    int ty = (int)(threadIdx.x >> 6);
    const float* fb = feat + (size_t)b * CC * NN + n0;
#pragma unroll
    for (int r = 0; r < 16; ++r) {
      int c = r * 4 + ty;
      tile[c][tx] = fb[(size_t)c * NN + tx];
    }
    __syncthreads();
    float* ob = featT + ((size_t)b * NN + n0) * CC;
#pragma unroll
    for (int r = 0; r < 16; ++r) {
      int n = r * 4 + ty;
      ob[(size_t)n * CC + tx] = tile[tx][n];
    }
  }
}

__global__ __launch_bounds__(GT) void qg_gather2(
    const float* __restrict__ xyz, const float* __restrict__ nxyz,
    const float* __restrict__ featT, const int* __restrict__ fps,
    const int* __restrict__ wsidx, float* __restrict__ out) {
  __shared__ float sf[CC][SCH * KK + 1];
  __shared__ int sidx[SCH * KK];
  const int tid = (int)threadIdx.x;
  const int blk = (int)blockIdx.x;
  const int b = blk >> 9;
  const int s0 = (blk & 511) * SCH;
  const size_t cstr = (size_t)SS * KK;

  if (tid < SCH * KK) {
    int s4 = tid / KK, k = tid - s4 * KK;
    int q = b * SS + s0 + s4;
    sidx[tid] = (k == 0) ? fps[q] : wsidx[(size_t)q * NS + (k - 1)];
  }
  __syncthreads();

  const float4* fT4 = (const float4*)(featT + (size_t)b * NN * CC);
  int e = tid & 15;
  for (int pp = tid >> 4; pp < SCH * KK; pp += GT / 16) {
    int n = sidx[pp];
    float4 v = fT4[(size_t)n * (CC / 4) + e];
    sf[4 * e + 0][pp] = v.x;
    sf[4 * e + 1][pp] = v.y;
    sf[4 * e + 2][pp] = v.z;
    sf[4 * e + 3][pp] = v.w;
  }

  if (tid < SCH * KK) {
    int s4 = tid / KK;
    int n = sidx[tid];
    const float* p = xyz + ((size_t)b * NN + n) * 3;
    float x = p[0], y = p[1], z = p[2];
    int q = b * SS + s0 + s4;
    float cx = nxyz[q * 3 + 0], cy = nxyz[q * 3 + 1], cz = nxyz[q * 3 + 2];
    size_t obase = ((size_t)(b * OC) * SS + s0) * KK + tid;
    out[obase + 0 * cstr] = x;
    out[obase + 1 * cstr] = y;
    out[obase + 2 * cstr] = z;
    out[obase + 3 * cstr] = x - cx;
    out[obase + 4 * cstr] = y - cy;
    out[obase + 5 * cstr] = z - cz;
  }
  __syncthreads();

  size_t fbase = ((size_t)(b * OC + 6) * SS + s0) * KK;
  for (int idx = tid; idx < CC * SCH * KK; idx += GT) {
    int c = idx / (SCH * KK);
    int j = idx - c * (SCH * KK);
    out[fbase + (size_t)c * cstr + j] = sf[c][j];
  }
}

__global__ __launch_bounds__(256) void qg_ballq(
    const float* __restrict__ xyz, const float* __restrict__ nxyz,
    int* __restrict__ wsidx) {
  int q = (int)((blockIdx.x * blockDim.x + threadIdx.x) >> 6);
  int lane = (int)(threadIdx.x & 63);
  int b = q / SS;
  const float* xb = xyz + (size_t)b * NN * 3;
  ball_query_wave(xb, nxyz[q * 3], nxyz[q * 3 + 1], nxyz[q * 3 + 2], lane,
                  wsidx + (size_t)q * NS);
}

__global__ __launch_bounds__(256) void qg_gather(
    const float* __restrict__ xyz, const float* __restrict__ nxyz,
    const float* __restrict__ feat, const int* __restrict__ fps,
    const int* __restrict__ wsidx, float* __restrict__ out) {
  unsigned t = blockIdx.x * 256u + threadIdx.x;
  const unsigned TOT = (unsigned)BB * OC * SS * KK;
  if (t >= TOT) return;
  unsigned k = t % KK;
  unsigned r = t / KK;
  unsigned s = r % SS;
  r /= SS;
  unsigned c = r % OC;
  unsigned b = r / OC;
  unsigned q = b * SS + s;
  int n = (k == 0) ? fps[q] : wsidx[(size_t)q * NS + (k - 1)];
  float v;
  if (c < 6) {
    unsigned cc = (c < 3) ? c : c - 3;
    v = xyz[((size_t)b * NN + (unsigned)n) * 3 + cc];
    if (c >= 3) v -= nxyz[q * 3 + cc];
  } else {
    v = feat[((size_t)b * CC + (c - 6)) * NN + (unsigned)n];
  }
  out[t] = v;
}

__global__ __launch_bounds__(256) void qg_fused(
    const float* __restrict__ xyz, const float* __restrict__ nxyz,
    const float* __restrict__ feat, const int* __restrict__ fps,
    float* __restrict__ out) {
  __shared__ int sidx[4][KK];
  int wv = (int)(threadIdx.x >> 6), lane = (int)(threadIdx.x & 63);
  int q = (int)blockIdx.x * 4 + wv;
  int b = q / SS, s = q % SS;
  const float* xb = xyz + (size_t)b * NN * 3;
  ball_query_wave(xb, nxyz[q * 3], nxyz[q * 3 + 1], nxyz[q * 3 + 2], lane,
                  &sidx[wv][1]);
  if (lane == 0) sidx[wv][0] = fps[q];
  __syncthreads();
  for (int f = lane; f < OC * KK; f += 64) {
    int c = f / KK, k = f - c * KK;
    int n = sidx[wv][k];
    float v;
    if (c < 6) {
      int cc = (c < 3) ? c : c - 3;
      v = xb[n * 3 + cc];
      if (c >= 3) v -= nxyz[q * 3 + cc];
    } else {
      v = feat[((size_t)b * CC + (c - 6)) * NN + n];
    }
    out[((size_t)((size_t)b * OC + c) * SS + s) * KK + k] = v;
  }
}

extern "C" void kernel_launch(void* const* d_in, const int* in_sizes, int n_in,
                              void* d_out, int out_size, void* d_ws, size_t ws_size,
                              hipStream_t stream) {
  const float* xyz  = (const float*)d_in[0];   // (B, N, 3)
  const float* nxyz = (const float*)d_in[1];   // (B, S, 3)
  const float* feat = (const float*)d_in[2];   // (B, C, N)
  const int*   fps  = (const int*)d_in[3];     // (B, S)
  float* out = (float*)d_out;                  // (B, 70, S, 33)

  const size_t idx_b   = (size_t)BB * SS * NS * sizeof(int);     // 1 MiB
  const size_t pts_b   = (size_t)BB * NN * sizeof(float4);       // 1 MiB
  const size_t off_b   = 16384;
  const size_t woff_b  = 16384;
  const size_t featT_b = (size_t)BB * NN * CC * sizeof(float);   // 16.8 MB
  const size_t grid_need = idx_b + pts_b + off_b + woff_b + featT_b;

  if (ws_size >= grid_need) {
    char* w = (char*)d_ws;
    /* wsidx (unused in main path) */                w += idx_b;
    float4* pts   = (float4*)w;                      w += pts_b;
    int*    off   = (int*)w;                         w += off_b;
    int*    woff  = (int*)w;                         w += woff_b;
    float*  featT = (float*)w;
    qg_build_tr<<<BB + 1024, 256, 0, stream>>>(xyz, feat, off, woff, featT);
    qg_scatter<<<(BB * NN) / 256, 256, 0, stream>>>(xyz, woff, pts);
    qg_main<<<BB * (SS / SCH), GT, 0, stream>>>(xyz, nxyz, pts, off, featT,
                                                fps, out);
  } else if (ws_size >= idx_b + featT_b) {
    int* wsidx = (int*)d_ws;
    float* featT = (float*)((char*)d_ws + idx_b);
    qg_prep<<<3072, 256, 0, stream>>>(xyz, nxyz, feat, wsidx, featT);
    qg_gather2<<<BB * (SS / SCH), GT, 0, stream>>>(xyz, nxyz, featT, fps,
                                                   wsidx, out);
  } else if (ws_size >= idx_b) {
    int* wsidx = (int*)d_ws;
    qg_ballq<<<(BB * SS) / 4, 256, 0, stream>>>(xyz, nxyz, wsidx);
    unsigned tot = (unsigned)BB * OC * SS * KK;
    qg_gather<<<(tot + 255u) / 256u, 256, 0, stream>>>(xyz, nxyz, feat, fps,
                                                       wsidx, out);
  } else {
    qg_fused<<<(BB * SS) / 4, 256, 0, stream>>>(xyz, nxyz, feat, fps, out);
  }
}

// Round 6
// 65.630 us; speedup vs baseline: 1.1759x; 1.0022x over previous
//
#include <hip/hip_runtime.h>

#define BB 4
#define NN 16384
#define SS 2048
#define CC 64
#define NS 32
#define KK 33   // NS + 1 (fps_idx prepended)
#define OC 70   // 3 raw xyz + 3 centered xyz + 64 features
#define SCH 4   // s-chunk per main block
#define GT 512  // gather/main block threads
#define NC 10
#define NCELL 1000
#define HCAP 224         // per-wave hit buffer cap (avg hits ~62)
#define RPAD 0.100001f   // cell-range pad (covers fp rounding of d2 test)

// --- prevent fma contraction so d2 matches the np/jax fp32 reference ---
__device__ __forceinline__ float sq_nofma(float v) {
  float r = v * v;
  asm volatile("" : "+v"(r));
  return r;
}

__device__ __forceinline__ int cell1(float x) {
  int c = (int)(x * 10.0f);
  return c < 0 ? 0 : (c > 9 ? 9 : c);
}
__device__ __forceinline__ int cell3(float x, float y, float z) {
  return (cell1(z) * NC + cell1(y)) * NC + cell1(x);
}

// ---------------- legacy wave ball-query (fallback + overflow path) -------
__device__ __forceinline__ void ball_query_wave(
    const float* __restrict__ xb, float qx, float qy, float qz, int lane,
    int* out) {
  const float R2 = 0.01f;
  int cnt = 0;
  int firstIdx = 0;
  for (int base = 0; base < NN; base += 256) {
    float px[4], py[4], pz[4];
#pragma unroll
    for (int j = 0; j < 4; ++j) {
      int n = base + j * 64 + lane;
      const float* p = xb + n * 3;
      px[j] = p[0]; py[j] = p[1]; pz[j] = p[2];
    }
#pragma unroll
    for (int j = 0; j < 4; ++j) {
      float dx = px[j] - qx, dy = py[j] - qy, dz = pz[j] - qz;
      float d2 = sq_nofma(dx) + sq_nofma(dy);
      asm volatile("" : "+v"(d2));
      d2 = d2 + sq_nofma(dz);
      bool m = d2 < R2;
      unsigned long long bal = __ballot(m);
      if (cnt == 0 && bal) firstIdx = base + j * 64 + __builtin_ctzll(bal);
      int pos = cnt + (int)__popcll(bal & ((1ull << lane) - 1ull));
      if (m && pos < NS) out[pos] = base + j * 64 + lane;
      cnt += (int)__popcll(bal);
    }
    if (cnt >= NS) break;
  }
  if (cnt < NS) {
    int pad = (cnt == 0) ? 0 : firstIdx;
    if (lane >= cnt && lane < NS) out[lane] = pad;
  }
}

// ---------------- K1: float4 transpose + parallel global-atomic hist ------
// 512 blocks: bid -> (b, n0 in 256-steps, cc in {0,1} = 32-channel half).
// cc==0 blocks also histogram their 256 points into hist[b*1024+cell].
__global__ __launch_bounds__(256) void qg_tr_hist(
    const float* __restrict__ xyz, const float* __restrict__ feat,
    float* __restrict__ featT, int* __restrict__ hist) {
  __shared__ float tile[32 * 260];  // 32 rows, stride 260 (pad kills conflicts)
  const int bid = (int)blockIdx.x;
  const int tid = (int)threadIdx.x;
  const int b = bid >> 7;
  const int rest = bid & 127;
  const int n0 = (rest >> 1) << 8;  // 0,256,...,16128
  const int cc = rest & 1;
  const int c0 = cc << 5;  // 0 or 32
  const int wv = tid >> 6, lane = tid & 63;

  if (cc == 0) {  // histogram this block's 256 points (global atomics)
    const float* p = xyz + ((size_t)b * NN + n0 + tid) * 3;
    atomicAdd(&hist[b * 1024 + cell3(p[0], p[1], p[2])], 1);
  }

  const float* fb = feat + ((size_t)b * CC + c0) * NN + n0;
#pragma unroll
  for (int rr = 0; rr < 8; ++rr) {
    int c = rr * 4 + wv;  // 0..31
    float4 v = *(const float4*)(fb + (size_t)c * NN + 4 * lane);
    *(float4*)&tile[c * 260 + 4 * lane] = v;
  }
  __syncthreads();
  const int c4 = lane & 7, m = lane >> 3;
  float4* oT = (float4*)(featT + ((size_t)b * NN + n0) * CC);
#pragma unroll
  for (int it = 0; it < 8; ++it) {
    int n = it * 32 + wv * 8 + m;  // 0..255
    float4 v;
    v.x = tile[(4 * c4 + 0) * 260 + n];
    v.y = tile[(4 * c4 + 1) * 260 + n];
    v.z = tile[(4 * c4 + 2) * 260 + n];
    v.w = tile[(4 * c4 + 3) * 260 + n];
    oT[(size_t)n * (CC / 4) + (c0 >> 2) + c4] = v;
  }
}

// ---------------- K1b: per-batch exclusive scan (4 tiny blocks) -----------
__global__ __launch_bounds__(256) void qg_scan(
    const int* __restrict__ hist, int* __restrict__ off,
    int* __restrict__ woff) {
  __shared__ int sc[256];
  const int b = (int)blockIdx.x;
  const int tid = (int)threadIdx.x;
  const int* hb = hist + b * 1024;
  int base = tid * 4;
  int l0 = (base + 0 < NCELL) ? hb[base + 0] : 0;
  int l1 = (base + 1 < NCELL) ? hb[base + 1] : 0;
  int l2 = (base + 2 < NCELL) ? hb[base + 2] : 0;
  int l3 = (base + 3 < NCELL) ? hb[base + 3] : 0;
  int s1 = l0, s2 = l0 + l1, s3 = l0 + l1 + l2, tot = s3 + l3;
  sc[tid] = tot;
  __syncthreads();
  for (int d = 1; d < 256; d <<= 1) {
    int v = (tid >= d) ? sc[tid - d] : 0;
    __syncthreads();
    sc[tid] += v;
    __syncthreads();
  }
  int ex = sc[tid] - tot;
  int* offb = off + b * (NCELL + 1);
  int* woffb = woff + b * NCELL;
  if (base + 0 < NCELL) { offb[base + 0] = ex;      woffb[base + 0] = ex; }
  if (base + 1 < NCELL) { offb[base + 1] = ex + s1; woffb[base + 1] = ex + s1; }
  if (base + 2 < NCELL) { offb[base + 2] = ex + s2; woffb[base + 2] = ex + s2; }
  if (base + 3 < NCELL) { offb[base + 3] = ex + s3; woffb[base + 3] = ex + s3; }
  if (tid == 0) offb[NCELL] = NN;
}

// ---------------- K2: counting-sort scatter (verified R3/R5) --------------
__global__ __launch_bounds__(256) void qg_scatter(
    const float* __restrict__ xyz, int* __restrict__ woff,
    float4* __restrict__ pts) {
  int i = (int)(blockIdx.x * 256u + threadIdx.x);  // 0..65535
  int b = i >> 14, n = i & (NN - 1);
  const float* p = xyz + ((size_t)b * NN + n) * 3;
  float x = p[0], y = p[1], z = p[2];
  int cell = cell3(x, y, z);
  int pos = atomicAdd(&woff[b * NCELL + cell], 1);
  pts[(b << 14) + pos] = make_float4(x, y, z, __int_as_float(n));
}

// ---------------- K3: fused grid ball-query + gather (float4 stores) ------
__global__ __launch_bounds__(GT) void qg_main(
    const float* __restrict__ xyz, const float* __restrict__ nxyz,
    const float4* __restrict__ pts, const int* __restrict__ off,
    const float* __restrict__ featT, const int* __restrict__ fps,
    float* __restrict__ out) {
  __shared__ float4 sf4[CC * KK];         // 64 rows x 33 float4 (132 floats)
  __shared__ float sxyz[6][SCH * KK];     // 6 x 132
  __shared__ int sidx[SCH * KK];          // 132
  __shared__ int hitbuf[SCH][HCAP];
  __shared__ int hcnt_s[SCH];
  float* sfl = (float*)sf4;
  const int tid = (int)threadIdx.x;
  const int blk = (int)blockIdx.x;  // 0..2047
  const int b = blk >> 9;
  const int s0 = (blk & 511) * SCH;
  const int wv = tid >> 6, lane = tid & 63;

  // ---- phase 1: ball query (waves 0..3, one query each) ----
  if (wv < SCH) {
    const int q = b * SS + s0 + wv;
    const float R2 = 0.01f;
    float qx = nxyz[q * 3 + 0];
    float qy = nxyz[q * 3 + 1];
    float qz = nxyz[q * 3 + 2];
    int* hb = hitbuf[wv];
    int* qout = &sidx[wv * KK];
    if (lane == 0) hcnt_s[wv] = 0;
    asm volatile("s_waitcnt lgkmcnt(0)" ::: "memory");

    int lox = max(0, (int)floorf((qx - RPAD) * 10.f));
    int hix = min(9, (int)floorf((qx + RPAD) * 10.f));
    int loy = max(0, (int)floorf((qy - RPAD) * 10.f));
    int hiy = min(9, (int)floorf((qy + RPAD) * 10.f));
    int loz = max(0, (int)floorf((qz - RPAD) * 10.f));
    int hiz = min(9, (int)floorf((qz + RPAD) * 10.f));

    // hoist span bounds: lane i in [0,9) owns span (loz+i/3, loy+i%3)
    const int* offb = off + b * (NCELL + 1);
    int start_l = 0, end_l = 0;
    {
      int cz = loz + lane / 3, cy = loy + lane % 3;
      if (lane < 9 && cz <= hiz && cy <= hiy) {
        int row = (cz * NC + cy) * NC;
        start_l = offb[row + lox];
        end_l = offb[row + hix + 1];
      }
    }
    const float4* pb = pts + ((size_t)b << 14);
    // dependence-free candidate loop: loads pipeline, no per-iter ballot
    for (int sp = 0; sp < 9; ++sp) {
      int start = __shfl(start_l, sp, 64);
      int end = __shfl(end_l, sp, 64);
      for (int p0 = start; p0 < end; p0 += 64) {
        int ii = p0 + lane;
        bool valid = ii < end;
        float4 v = pb[valid ? ii : (end - 1)];
        float dx = v.x - qx, dy = v.y - qy, dz = v.z - qz;
        float d2 = sq_nofma(dx) + sq_nofma(dy);
        asm volatile("" : "+v"(d2));
        d2 = d2 + sq_nofma(dz);
        if (valid && d2 < R2) {
          int pos = atomicAdd(&hcnt_s[wv], 1);
          if (pos < HCAP) hb[pos] = __float_as_int(v.w);
        }
      }
    }
    asm volatile("s_waitcnt lgkmcnt(0)" ::: "memory");
    const int M = hcnt_s[wv];
    if (M > HCAP) {
      // safety net: exact legacy linear scan (prob ~0 on this data)
      ball_query_wave(xyz + (size_t)b * NN * 3, qx, qy, qz, lane, qout + 1);
    } else {
      // rank by original index = output position (order-independent)
      int minv = 0x7fffffff;
      for (int i = lane; i < M; i += 64) {
        int hh = hb[i];
        minv = min(minv, hh);
        int rank = 0;
        for (int j = 0; j < M; ++j) rank += (hb[j] < hh) ? 1 : 0;
        if (rank < NS) qout[1 + rank] = hh;
      }
      if (M < NS) {
#pragma unroll
        for (int d = 1; d < 64; d <<= 1)
          minv = min(minv, __shfl_xor(minv, d, 64));
        int pad = (M == 0) ? 0 : minv;
        if (lane >= M && lane < NS) qout[1 + lane] = pad;
      }
    }
    if (lane == 0) qout[0] = fps[q];
  }
  __syncthreads();

  // ---- phase 2: gather to LDS (all 512 threads) ----
  const float4* fT4 = (const float4*)(featT + (size_t)b * NN * CC);
  int e = tid & 15;
  for (int pp = tid >> 4; pp < SCH * KK; pp += GT / 16) {
    int n = sidx[pp];
    float4 v = fT4[(size_t)n * (CC / 4) + e];
    sfl[(4 * e + 0) * (SCH * KK) + pp] = v.x;
    sfl[(4 * e + 1) * (SCH * KK) + pp] = v.y;
    sfl[(4 * e + 2) * (SCH * KK) + pp] = v.z;
    sfl[(4 * e + 3) * (SCH * KK) + pp] = v.w;
  }
  if (tid < SCH * KK) {
    int s4 = tid / KK;
    int n = sidx[tid];
    const float* p = xyz + ((size_t)b * NN + n) * 3;
    float x = p[0], y = p[1], z = p[2];
    int q = b * SS + s0 + s4;
    float cx = nxyz[q * 3 + 0], cy = nxyz[q * 3 + 1], cz = nxyz[q * 3 + 2];
    sxyz[0][tid] = x;
    sxyz[1][tid] = y;
    sxyz[2][tid] = z;
    sxyz[3][tid] = x - cx;
    sxyz[4][tid] = y - cy;
    sxyz[5][tid] = z - cz;
  }
  __syncthreads();

  // ---- phase 3: unified float4 store of all 70 channel rows ----
  float4* out4 = (float4*)out;
  const size_t cstr4 = (size_t)SS * KK / 4;  // 16896
  size_t obase4 = (size_t)b * OC * cstr4 + (size_t)(blk & 511) * KK;
  for (int idx = tid; idx < OC * KK; idx += GT) {
    int c = idx / KK, j4 = idx - c * KK;
    float4 v;
    if (c < 6) {
      v.x = sxyz[c][4 * j4 + 0];
      v.y = sxyz[c][4 * j4 + 1];
      v.z = sxyz[c][4 * j4 + 2];
      v.w = sxyz[c][4 * j4 + 3];
    } else {
      v = sf4[(c - 6) * KK + j4];
    }
    out4[obase4 + (size_t)c * cstr4 + j4] = v;
  }
}

// ---------------- legacy fallback kernels (small-ws paths) ----------------
__global__ __launch_bounds__(256) void qg_prep(
    const float* __restrict__ xyz, const float* __restrict__ nxyz,
    const float* __restrict__ feat, int* __restrict__ wsidx,
    float* __restrict__ featT) {
  __shared__ float tile[64][65];
  int bid = (int)blockIdx.x;
  int r3 = bid % 3;
  if (r3 < 2) {
    int lane = (int)(threadIdx.x & 63);
    int q = ((bid / 3) * 2 + r3) * 4 + (int)(threadIdx.x >> 6);
    int b = q >> 11;
    const float* xb = xyz + (size_t)b * NN * 3;
    ball_query_wave(xb, nxyz[q * 3], nxyz[q * 3 + 1], nxyz[q * 3 + 2], lane,
                    wsidx + (size_t)q * NS);
  } else {
    int tb = bid / 3;
    int b = tb >> 8;
    int n0 = (tb & 255) << 6;
    int tx = (int)(threadIdx.x & 63);
    int ty = (int)(threadIdx.x >> 6);
    const float* fb = feat + (size_t)b * CC * NN + n0;
#pragma unroll
    for (int r = 0; r < 16; ++r) {
      int c = r * 4 + ty;
      tile[c][tx] = fb[(size_t)c * NN + tx];
    }
    __syncthreads();
    float* ob = featT + ((size_t)b * NN + n0) * CC;
#pragma unroll
    for (int r = 0; r < 16; ++r) {
      int n = r * 4 + ty;
      ob[(size_t)n * CC + tx] = tile[tx][n];
    }
  }
}

__global__ __launch_bounds__(GT) void qg_gather2(
    const float* __restrict__ xyz, const float* __restrict__ nxyz,
    const float* __restrict__ featT, const int* __restrict__ fps,
    const int* __restrict__ wsidx, float* __restrict__ out) {
  __shared__ float sf[CC][SCH * KK + 1];
  __shared__ int sidx[SCH * KK];
  const int tid = (int)threadIdx.x;
  const int blk = (int)blockIdx.x;
  const int b = blk >> 9;
  const int s0 = (blk & 511) * SCH;
  const size_t cstr = (size_t)SS * KK;

  if (tid < SCH * KK) {
    int s4 = tid / KK, k = tid - s4 * KK;
    int q = b * SS + s0 + s4;
    sidx[tid] = (k == 0) ? fps[q] : wsidx[(size_t)q * NS + (k - 1)];
  }
  __syncthreads();

  const float4* fT4 = (const float4*)(featT + (size_t)b * NN * CC);
  int e = tid & 15;
  for (int pp = tid >> 4; pp < SCH * KK; pp += GT / 16) {
    int n = sidx[pp];
    float4 v = fT4[(size_t)n * (CC / 4) + e];
    sf[4 * e + 0][pp] = v.x;
    sf[4 * e + 1][pp] = v.y;
    sf[4 * e + 2][pp] = v.z;
    sf[4 * e + 3][pp] = v.w;
  }

  if (tid < SCH * KK) {
    int s4 = tid / KK;
    int n = sidx[tid];
    const float* p = xyz + ((size_t)b * NN + n) * 3;
    float x = p[0], y = p[1], z = p[2];
    int q = b * SS + s0 + s4;
    float cx = nxyz[q * 3 + 0], cy = nxyz[q * 3 + 1], cz = nxyz[q * 3 + 2];
    size_t obase = ((size_t)(b * OC) * SS + s0) * KK + tid;
    out[obase + 0 * cstr] = x;
    out[obase + 1 * cstr] = y;
    out[obase + 2 * cstr] = z;
    out[obase + 3 * cstr] = x - cx;
    out[obase + 4 * cstr] = y - cy;
    out[obase + 5 * cstr] = z - cz;
  }
  __syncthreads();

  size_t fbase = ((size_t)(b * OC + 6) * SS + s0) * KK;
  for (int idx = tid; idx < CC * SCH * KK; idx += GT) {
    int c = idx / (SCH * KK);
    int j = idx - c * (SCH * KK);
    out[fbase + (size_t)c * cstr + j] = sf[c][j];
  }
}

__global__ __launch_bounds__(256) void qg_ballq(
    const float* __restrict__ xyz, const float* __restrict__ nxyz,
    int* __restrict__ wsidx) {
  int q = (int)((blockIdx.x * blockDim.x + threadIdx.x) >> 6);
  int lane = (int)(threadIdx.x & 63);
  int b = q / SS;
  const float* xb = xyz + (size_t)b * NN * 3;
  ball_query_wave(xb, nxyz[q * 3], nxyz[q * 3 + 1], nxyz[q * 3 + 2], lane,
                  wsidx + (size_t)q * NS);
}

__global__ __launch_bounds__(256) void qg_gather(
    const float* __restrict__ xyz, const float* __restrict__ nxyz,
    const float* __restrict__ feat, const int* __restrict__ fps,
    const int* __restrict__ wsidx, float* __restrict__ out) {
  unsigned t = blockIdx.x * 256u + threadIdx.x;
  const unsigned TOT = (unsigned)BB * OC * SS * KK;
  if (t >= TOT) return;
  unsigned k = t % KK;
  unsigned r = t / KK;
  unsigned s = r % SS;
  r /= SS;
  unsigned c = r % OC;
  unsigned b = r / OC;
  unsigned q = b * SS + s;
  int n = (k == 0) ? fps[q] : wsidx[(size_t)q * NS + (k - 1)];
  float v;
  if (c < 6) {
    unsigned cc = (c < 3) ? c : c - 3;
    v = xyz[((size_t)b * NN + (unsigned)n) * 3 + cc];
    if (c >= 3) v -= nxyz[q * 3 + cc];
  } else {
    v = feat[((size_t)b * CC + (c - 6)) * NN + (unsigned)n];
  }
  out[t] = v;
}

__global__ __launch_bounds__(256) void qg_fused(
    const float* __restrict__ xyz, const float* __restrict__ nxyz,
    const float* __restrict__ feat, const int* __restrict__ fps,
    float* __restrict__ out) {
  __shared__ int sidx[4][KK];
  int wv = (int)(threadIdx.x >> 6), lane = (int)(threadIdx.x & 63);
  int q = (int)blockIdx.x * 4 + wv;
  int b = q / SS, s = q % SS;
  const float* xb = xyz + (size_t)b * NN * 3;
  ball_query_wave(xb, nxyz[q * 3], nxyz[q * 3 + 1], nxyz[q * 3 + 2], lane,
                  &sidx[wv][1]);
  if (lane == 0) sidx[wv][0] = fps[q];
  __syncthreads();
  for (int f = lane; f < OC * KK; f += 64) {
    int c = f / KK, k = f - c * KK;
    int n = sidx[wv][k];
    float v;
    if (c < 6) {
      int cc = (c < 3) ? c : c - 3;
      v = xb[n * 3 + cc];
      if (c >= 3) v -= nxyz[q * 3 + cc];
    } else {
      v = feat[((size_t)b * CC + (c - 6)) * NN + n];
    }
    out[((size_t)((size_t)b * OC + c) * SS + s) * KK + k] = v;
  }
}

extern "C" void kernel_launch(void* const* d_in, const int* in_sizes, int n_in,
                              void* d_out, int out_size, void* d_ws, size_t ws_size,
                              hipStream_t stream) {
  const float* xyz  = (const float*)d_in[0];   // (B, N, 3)
  const float* nxyz = (const float*)d_in[1];   // (B, S, 3)
  const float* feat = (const float*)d_in[2];   // (B, C, N)
  const int*   fps  = (const int*)d_in[3];     // (B, S)
  float* out = (float*)d_out;                  // (B, 70, S, 33)

  const size_t pts_b   = (size_t)BB * NN * sizeof(float4);       // 1 MiB
  const size_t off_b   = 16384;
  const size_t hist_b  = (size_t)BB * 1024 * sizeof(int);        // 16 KB
  const size_t woff_b  = 16384;
  const size_t featT_b = (size_t)BB * NN * CC * sizeof(float);   // 16.8 MB
  const size_t grid_need = pts_b + off_b + hist_b + woff_b + featT_b;

  const size_t idx_b = (size_t)BB * SS * NS * sizeof(int);       // fallback

  if (ws_size >= grid_need) {
    char* w = (char*)d_ws;
    float4* pts   = (float4*)w;                      w += pts_b;
    int*    off   = (int*)w;                         w += off_b;
    int*    hist  = (int*)w;                         w += hist_b;
    int*    woff  = (int*)w;                         w += woff_b;
    float*  featT = (float*)w;
    hipMemsetAsync(hist, 0, hist_b, stream);
    qg_tr_hist<<<512, 256, 0, stream>>>(xyz, feat, featT, hist);
    qg_scan<<<BB, 256, 0, stream>>>(hist, off, woff);
    qg_scatter<<<(BB * NN) / 256, 256, 0, stream>>>(xyz, woff, pts);
    qg_main<<<BB * (SS / SCH), GT, 0, stream>>>(xyz, nxyz, pts, off, featT,
                                                fps, out);
  } else if (ws_size >= idx_b + featT_b) {
    int* wsidx = (int*)d_ws;
    float* featT = (float*)((char*)d_ws + idx_b);
    qg_prep<<<3072, 256, 0, stream>>>(xyz, nxyz, feat, wsidx, featT);
    qg_gather2<<<BB * (SS / SCH), GT, 0, stream>>>(xyz, nxyz, featT, fps,
                                                   wsidx, out);
  } else if (ws_size >= idx_b) {
    int* wsidx = (int*)d_ws;
    qg_ballq<<<(BB * SS) / 4, 256, 0, stream>>>(xyz, nxyz, wsidx);
    unsigned tot = (unsigned)BB * OC * SS * KK;
    qg_gather<<<(tot + 255u) / 256u, 256, 0, stream>>>(xyz, nxyz, feat, fps,
                                                       wsidx, out);
  } else {
    qg_fused<<<(BB * SS) / 4, 256, 0, stream>>>(xyz, nxyz, feat, fps, out);
  }
}

// Round 7
// 58.491 us; speedup vs baseline: 1.3194x; 1.1221x over previous
//
#include <hip/hip_runtime.h>

#define BB 4
#define NN 16384
#define SS 2048
#define CC 64
#define NS 32
#define KK 33   // NS + 1 (fps_idx prepended)
#define OC 70   // 3 raw xyz + 3 centered xyz + 64 features
#define SCH 4   // s-chunk per main block
#define GT 512  // gather/main block threads
#define NC 10
#define NCELL 1000
#define HCAP 224         // per-wave hit buffer cap (avg hits ~62)
#define RPAD 0.100001f   // cell-range pad (covers fp rounding of d2 test)

// --- prevent fma contraction so d2 matches the np/jax fp32 reference ---
__device__ __forceinline__ float sq_nofma(float v) {
  float r = v * v;
  asm volatile("" : "+v"(r));
  return r;
}

__device__ __forceinline__ int cell1(float x) {
  int c = (int)(x * 10.0f);
  return c < 0 ? 0 : (c > 9 ? 9 : c);
}
__device__ __forceinline__ int cell3(float x, float y, float z) {
  return (cell1(z) * NC + cell1(y)) * NC + cell1(x);
}

// ---------------- legacy wave ball-query (fallback + overflow path) -------
__device__ __forceinline__ void ball_query_wave(
    const float* __restrict__ xb, float qx, float qy, float qz, int lane,
    int* out) {
  const float R2 = 0.01f;
  int cnt = 0;
  int firstIdx = 0;
  for (int base = 0; base < NN; base += 256) {
    float px[4], py[4], pz[4];
#pragma unroll
    for (int j = 0; j < 4; ++j) {
      int n = base + j * 64 + lane;
      const float* p = xb + n * 3;
      px[j] = p[0]; py[j] = p[1]; pz[j] = p[2];
    }
#pragma unroll
    for (int j = 0; j < 4; ++j) {
      float dx = px[j] - qx, dy = py[j] - qy, dz = pz[j] - qz;
      float d2 = sq_nofma(dx) + sq_nofma(dy);
      asm volatile("" : "+v"(d2));
      d2 = d2 + sq_nofma(dz);
      bool m = d2 < R2;
      unsigned long long bal = __ballot(m);
      if (cnt == 0 && bal) firstIdx = base + j * 64 + __builtin_ctzll(bal);
      int pos = cnt + (int)__popcll(bal & ((1ull << lane) - 1ull));
      if (m && pos < NS) out[pos] = base + j * 64 + lane;
      cnt += (int)__popcll(bal);
    }
    if (cnt >= NS) break;
  }
  if (cnt < NS) {
    int pad = (cnt == 0) ? 0 : firstIdx;
    if (lane >= cnt && lane < NS) out[lane] = pad;
  }
}

// ---------------- K1: float4 transpose + parallel global-atomic hist ------
// (verified R6) 512 blocks: bid -> (b, n0 in 256-steps, cc in {0,1}).
__global__ __launch_bounds__(256) void qg_tr_hist(
    const float* __restrict__ xyz, const float* __restrict__ feat,
    float* __restrict__ featT, int* __restrict__ hist) {
  __shared__ float tile[32 * 260];  // 32 rows, stride 260 (pad kills conflicts)
  const int bid = (int)blockIdx.x;
  const int tid = (int)threadIdx.x;
  const int b = bid >> 7;
  const int rest = bid & 127;
  const int n0 = (rest >> 1) << 8;  // 0,256,...,16128
  const int cc = rest & 1;
  const int c0 = cc << 5;  // 0 or 32
  const int wv = tid >> 6, lane = tid & 63;

  if (cc == 0) {  // histogram this block's 256 points (global atomics)
    const float* p = xyz + ((size_t)b * NN + n0 + tid) * 3;
    atomicAdd(&hist[b * 1024 + cell3(p[0], p[1], p[2])], 1);
  }

  const float* fb = feat + ((size_t)b * CC + c0) * NN + n0;
#pragma unroll
  for (int rr = 0; rr < 8; ++rr) {
    int c = rr * 4 + wv;  // 0..31
    float4 v = *(const float4*)(fb + (size_t)c * NN + 4 * lane);
    *(float4*)&tile[c * 260 + 4 * lane] = v;
  }
  __syncthreads();
  const int c4 = lane & 7, m = lane >> 3;
  float4* oT = (float4*)(featT + ((size_t)b * NN + n0) * CC);
#pragma unroll
  for (int it = 0; it < 8; ++it) {
    int n = it * 32 + wv * 8 + m;  // 0..255
    float4 v;
    v.x = tile[(4 * c4 + 0) * 260 + n];
    v.y = tile[(4 * c4 + 1) * 260 + n];
    v.z = tile[(4 * c4 + 2) * 260 + n];
    v.w = tile[(4 * c4 + 3) * 260 + n];
    oT[(size_t)n * (CC / 4) + (c0 >> 2) + c4] = v;
  }
}

// ---------------- K1b: per-batch exclusive scan (4 tiny blocks) -----------
__global__ __launch_bounds__(256) void qg_scan(
    const int* __restrict__ hist, int* __restrict__ off,
    int* __restrict__ woff) {
  __shared__ int sc[256];
  const int b = (int)blockIdx.x;
  const int tid = (int)threadIdx.x;
  const int* hb = hist + b * 1024;
  int base = tid * 4;
  int l0 = (base + 0 < NCELL) ? hb[base + 0] : 0;
  int l1 = (base + 1 < NCELL) ? hb[base + 1] : 0;
  int l2 = (base + 2 < NCELL) ? hb[base + 2] : 0;
  int l3 = (base + 3 < NCELL) ? hb[base + 3] : 0;
  int s1 = l0, s2 = l0 + l1, s3 = l0 + l1 + l2, tot = s3 + l3;
  sc[tid] = tot;
  __syncthreads();
  for (int d = 1; d < 256; d <<= 1) {
    int v = (tid >= d) ? sc[tid - d] : 0;
    __syncthreads();
    sc[tid] += v;
    __syncthreads();
  }
  int ex = sc[tid] - tot;
  int* offb = off + b * (NCELL + 1);
  int* woffb = woff + b * NCELL;
  if (base + 0 < NCELL) { offb[base + 0] = ex;      woffb[base + 0] = ex; }
  if (base + 1 < NCELL) { offb[base + 1] = ex + s1; woffb[base + 1] = ex + s1; }
  if (base + 2 < NCELL) { offb[base + 2] = ex + s2; woffb[base + 2] = ex + s2; }
  if (base + 3 < NCELL) { offb[base + 3] = ex + s3; woffb[base + 3] = ex + s3; }
  if (tid == 0) offb[NCELL] = NN;
}

// ---------------- K2: counting-sort scatter (verified R3/R5/R6) -----------
__global__ __launch_bounds__(256) void qg_scatter(
    const float* __restrict__ xyz, int* __restrict__ woff,
    float4* __restrict__ pts) {
  int i = (int)(blockIdx.x * 256u + threadIdx.x);  // 0..65535
  int b = i >> 14, n = i & (NN - 1);
  const float* p = xyz + ((size_t)b * NN + n) * 3;
  float x = p[0], y = p[1], z = p[2];
  int cell = cell3(x, y, z);
  int pos = atomicAdd(&woff[b * NCELL + cell], 1);
  pts[(b << 14) + pos] = make_float4(x, y, z, __int_as_float(n));
}

// ---------------- K3: fused grid ball-query + gather (R4-verified form) ---
__global__ __launch_bounds__(GT) void qg_main(
    const float* __restrict__ xyz, const float* __restrict__ nxyz,
    const float4* __restrict__ pts, const int* __restrict__ off,
    const float* __restrict__ featT, const int* __restrict__ fps,
    float* __restrict__ out) {
  __shared__ float sf[CC][SCH * KK + 1];  // [64][133] padded: 0 bank conflicts
  __shared__ int sidx[SCH * KK];          // 132
  __shared__ int hitbuf[SCH][HCAP];
  __shared__ int hcnt_s[SCH];
  const int tid = (int)threadIdx.x;
  const int blk = (int)blockIdx.x;  // 0..2047
  const int b = blk >> 9;
  const int s0 = (blk & 511) * SCH;
  const int wv = tid >> 6, lane = tid & 63;

  // ---- phase 1: ball query (waves 0..3, one query each) ----
  if (wv < SCH) {
    const int q = b * SS + s0 + wv;
    const float R2 = 0.01f;
    float qx = nxyz[q * 3 + 0];
    float qy = nxyz[q * 3 + 1];
    float qz = nxyz[q * 3 + 2];
    int* hb = hitbuf[wv];
    int* qout = &sidx[wv * KK];
    if (lane == 0) hcnt_s[wv] = 0;
    asm volatile("s_waitcnt lgkmcnt(0)" ::: "memory");

    int lox = max(0, (int)floorf((qx - RPAD) * 10.f));
    int hix = min(9, (int)floorf((qx + RPAD) * 10.f));
    int loy = max(0, (int)floorf((qy - RPAD) * 10.f));
    int hiy = min(9, (int)floorf((qy + RPAD) * 10.f));
    int loz = max(0, (int)floorf((qz - RPAD) * 10.f));
    int hiz = min(9, (int)floorf((qz + RPAD) * 10.f));

    // hoist span bounds: lane i in [0,9) owns span (loz+i/3, loy+i%3)
    const int* offb = off + b * (NCELL + 1);
    int start_l = 0, end_l = 0;
    {
      int cz = loz + lane / 3, cy = loy + lane % 3;
      if (lane < 9 && cz <= hiz && cy <= hiy) {
        int row = (cz * NC + cy) * NC;
        start_l = offb[row + lox];
        end_l = offb[row + hix + 1];
      }
    }
    const float4* pb = pts + ((size_t)b << 14);
    // dependence-free candidate loop: loads pipeline, no per-iter ballot
    for (int sp = 0; sp < 9; ++sp) {
      int start = __shfl(start_l, sp, 64);
      int end = __shfl(end_l, sp, 64);
      for (int p0 = start; p0 < end; p0 += 64) {
        int ii = p0 + lane;
        bool valid = ii < end;
        float4 v = pb[valid ? ii : (end - 1)];
        float dx = v.x - qx, dy = v.y - qy, dz = v.z - qz;
        float d2 = sq_nofma(dx) + sq_nofma(dy);
        asm volatile("" : "+v"(d2));
        d2 = d2 + sq_nofma(dz);
        if (valid && d2 < R2) {
          int pos = atomicAdd(&hcnt_s[wv], 1);
          if (pos < HCAP) hb[pos] = __float_as_int(v.w);
        }
      }
    }
    asm volatile("s_waitcnt lgkmcnt(0)" ::: "memory");
    const int M = hcnt_s[wv];
    if (M > HCAP) {
      // safety net: exact legacy linear scan (prob ~0 on this data)
      ball_query_wave(xyz + (size_t)b * NN * 3, qx, qy, qz, lane, qout + 1);
    } else {
      // rank by original index = output position (order-independent)
      int minv = 0x7fffffff;
      for (int i = lane; i < M; i += 64) {
        int hh = hb[i];
        minv = min(minv, hh);
        int rank = 0;
        for (int j = 0; j < M; ++j) rank += (hb[j] < hh) ? 1 : 0;
        if (rank < NS) qout[1 + rank] = hh;
      }
      if (M < NS) {
#pragma unroll
        for (int d = 1; d < 64; d <<= 1)
          minv = min(minv, __shfl_xor(minv, d, 64));
        int pad = (M == 0) ? 0 : minv;
        if (lane >= M && lane < NS) qout[1 + lane] = pad;
      }
    }
    if (lane == 0) qout[0] = fps[q];
  }
  __syncthreads();

  // ---- phase 2: gather features -> padded LDS (all 512 threads) ----
  const size_t cstr = (size_t)SS * KK;
  const float4* fT4 = (const float4*)(featT + (size_t)b * NN * CC);
  int e = tid & 15;
  for (int pp = tid >> 4; pp < SCH * KK; pp += GT / 16) {
    int n = sidx[pp];
    float4 v = fT4[(size_t)n * (CC / 4) + e];
    sf[4 * e + 0][pp] = v.x;
    sf[4 * e + 1][pp] = v.y;
    sf[4 * e + 2][pp] = v.z;
    sf[4 * e + 3][pp] = v.w;
  }

  // xyz channels (0..5): direct coalesced scalar writes
  if (tid < SCH * KK) {
    int s4 = tid / KK;
    int n = sidx[tid];
    const float* p = xyz + ((size_t)b * NN + n) * 3;
    float x = p[0], y = p[1], z = p[2];
    int q = b * SS + s0 + s4;
    float cx = nxyz[q * 3 + 0], cy = nxyz[q * 3 + 1], cz = nxyz[q * 3 + 2];
    size_t obase = ((size_t)(b * OC) * SS + s0) * KK + tid;
    out[obase + 0 * cstr] = x;
    out[obase + 1 * cstr] = y;
    out[obase + 2 * cstr] = z;
    out[obase + 3 * cstr] = x - cx;
    out[obase + 4 * cstr] = y - cy;
    out[obase + 5 * cstr] = z - cz;
  }
  __syncthreads();

  // ---- phase 3: feature channel rows, linear scalar stores ----
  size_t fbase = ((size_t)(b * OC + 6) * SS + s0) * KK;
  for (int idx = tid; idx < CC * SCH * KK; idx += GT) {
    int c = idx / (SCH * KK);
    int j = idx - c * (SCH * KK);
    out[fbase + (size_t)c * cstr + j] = sf[c][j];
  }
}

// ---------------- legacy fallback kernels (small-ws paths) ----------------
__global__ __launch_bounds__(256) void qg_prep(
    const float* __restrict__ xyz, const float* __restrict__ nxyz,
    const float* __restrict__ feat, int* __restrict__ wsidx,
    float* __restrict__ featT) {
  __shared__ float tile[64][65];
  int bid = (int)blockIdx.x;
  int r3 = bid % 3;
  if (r3 < 2) {
    int lane = (int)(threadIdx.x & 63);
    int q = ((bid / 3) * 2 + r3) * 4 + (int)(threadIdx.x >> 6);
    int b = q >> 11;
    const float* xb = xyz + (size_t)b * NN * 3;
    ball_query_wave(xb, nxyz[q * 3], nxyz[q * 3 + 1], nxyz[q * 3 + 2], lane,
                    wsidx + (size_t)q * NS);
  } else {
    int tb = bid / 3;
    int b = tb >> 8;
    int n0 = (tb & 255) << 6;
    int tx = (int)(threadIdx.x & 63);
    int ty = (int)(threadIdx.x >> 6);
    const float* fb = feat + (size_t)b * CC * NN + n0;
#pragma unroll
    for (int r = 0; r < 16; ++r) {
      int c = r * 4 + ty;
      tile[c][tx] = fb[(size_t)c * NN + tx];
    }
    __syncthreads();
    float* ob = featT + ((size_t)b * NN + n0) * CC;
#pragma unroll
    for (int r = 0; r < 16; ++r) {
      int n = r * 4 + ty;
      ob[(size_t)n * CC + tx] = tile[tx][n];
    }
  }
}

__global__ __launch_bounds__(GT) void qg_gather2(
    const float* __restrict__ xyz, const float* __restrict__ nxyz,
    const float* __restrict__ featT, const int* __restrict__ fps,
    const int* __restrict__ wsidx, float* __restrict__ out) {
  __shared__ float sf[CC][SCH * KK + 1];
  __shared__ int sidx[SCH * KK];
  const int tid = (int)threadIdx.x;
  const int blk = (int)blockIdx.x;
  const int b = blk >> 9;
  const int s0 = (blk & 511) * SCH;
  const size_t cstr = (size_t)SS * KK;

  if (tid < SCH * KK) {
    int s4 = tid / KK, k = tid - s4 * KK;
    int q = b * SS + s0 + s4;
    sidx[tid] = (k == 0) ? fps[q] : wsidx[(size_t)q * NS + (k - 1)];
  }
  __syncthreads();

  const float4* fT4 = (const float4*)(featT + (size_t)b * NN * CC);
  int e = tid & 15;
  for (int pp = tid >> 4; pp < SCH * KK; pp += GT / 16) {
    int n = sidx[pp];
    float4 v = fT4[(size_t)n * (CC / 4) + e];
    sf[4 * e + 0][pp] = v.x;
    sf[4 * e + 1][pp] = v.y;
    sf[4 * e + 2][pp] = v.z;
    sf[4 * e + 3][pp] = v.w;
  }

  if (tid < SCH * KK) {
    int s4 = tid / KK;
    int n = sidx[tid];
    const float* p = xyz + ((size_t)b * NN + n) * 3;
    float x = p[0], y = p[1], z = p[2];
    int q = b * SS + s0 + s4;
    float cx = nxyz[q * 3 + 0], cy = nxyz[q * 3 + 1], cz = nxyz[q * 3 + 2];
    size_t obase = ((size_t)(b * OC) * SS + s0) * KK + tid;
    out[obase + 0 * cstr] = x;
    out[obase + 1 * cstr] = y;
    out[obase + 2 * cstr] = z;
    out[obase + 3 * cstr] = x - cx;
    out[obase + 4 * cstr] = y - cy;
    out[obase + 5 * cstr] = z - cz;
  }
  __syncthreads();

  size_t fbase = ((size_t)(b * OC + 6) * SS + s0) * KK;
  for (int idx = tid; idx < CC * SCH * KK; idx += GT) {
    int c = idx / (SCH * KK);
    int j = idx - c * (SCH * KK);
    out[fbase + (size_t)c * cstr + j] = sf[c][j];
  }
}

__global__ __launch_bounds__(256) void qg_ballq(
    const float* __restrict__ xyz, const float* __restrict__ nxyz,
    int* __restrict__ wsidx) {
  int q = (int)((blockIdx.x * blockDim.x + threadIdx.x) >> 6);
  int lane = (int)(threadIdx.x & 63);
  int b = q / SS;
  const float* xb = xyz + (size_t)b * NN * 3;
  ball_query_wave(xb, nxyz[q * 3], nxyz[q * 3 + 1], nxyz[q * 3 + 2], lane,
                  wsidx + (size_t)q * NS);
}

__global__ __launch_bounds__(256) void qg_gather(
    const float* __restrict__ xyz, const float* __restrict__ nxyz,
    const float* __restrict__ feat, const int* __restrict__ fps,
    const int* __restrict__ wsidx, float* __restrict__ out) {
  unsigned t = blockIdx.x * 256u + threadIdx.x;
  const unsigned TOT = (unsigned)BB * OC * SS * KK;
  if (t >= TOT) return;
  unsigned k = t % KK;
  unsigned r = t / KK;
  unsigned s = r % SS;
  r /= SS;
  unsigned c = r % OC;
  unsigned b = r / OC;
  unsigned q = b * SS + s;
  int n = (k == 0) ? fps[q] : wsidx[(size_t)q * NS + (k - 1)];
  float v;
  if (c < 6) {
    unsigned cc = (c < 3) ? c : c - 3;
    v = xyz[((size_t)b * NN + (unsigned)n) * 3 + cc];
    if (c >= 3) v -= nxyz[q * 3 + cc];
  } else {
    v = feat[((size_t)b * CC + (c - 6)) * NN + (unsigned)n];
  }
  out[t] = v;
}

__global__ __launch_bounds__(256) void qg_fused(
    const float* __restrict__ xyz, const float* __restrict__ nxyz,
    const float* __restrict__ feat, const int* __restrict__ fps,
    float* __restrict__ out) {
  __shared__ int sidx[4][KK];
  int wv = (int)(threadIdx.x >> 6), lane = (int)(threadIdx.x & 63);
  int q = (int)blockIdx.x * 4 + wv;
  int b = q / SS, s = q % SS;
  const float* xb = xyz + (size_t)b * NN * 3;
  ball_query_wave(xb, nxyz[q * 3], nxyz[q * 3 + 1], nxyz[q * 3 + 2], lane,
                  &sidx[wv][1]);
  if (lane == 0) sidx[wv][0] = fps[q];
  __syncthreads();
  for (int f = lane; f < OC * KK; f += 64) {
    int c = f / KK, k = f - c * KK;
    int n = sidx[wv][k];
    float v;
    if (c < 6) {
      int cc = (c < 3) ? c : c - 3;
      v = xb[n * 3 + cc];
      if (c >= 3) v -= nxyz[q * 3 + cc];
    } else {
      v = feat[((size_t)b * CC + (c - 6)) * NN + n];
    }
    out[((size_t)((size_t)b * OC + c) * SS + s) * KK + k] = v;
  }
}

extern "C" void kernel_launch(void* const* d_in, const int* in_sizes, int n_in,
                              void* d_out, int out_size, void* d_ws, size_t ws_size,
                              hipStream_t stream) {
  const float* xyz  = (const float*)d_in[0];   // (B, N, 3)
  const float* nxyz = (const float*)d_in[1];   // (B, S, 3)
  const float* feat = (const float*)d_in[2];   // (B, C, N)
  const int*   fps  = (const int*)d_in[3];     // (B, S)
  float* out = (float*)d_out;                  // (B, 70, S, 33)

  const size_t pts_b   = (size_t)BB * NN * sizeof(float4);       // 1 MiB
  const size_t off_b   = 16384;
  const size_t hist_b  = (size_t)BB * 1024 * sizeof(int);        // 16 KB
  const size_t woff_b  = 16384;
  const size_t featT_b = (size_t)BB * NN * CC * sizeof(float);   // 16.8 MB
  const size_t grid_need = pts_b + off_b + hist_b + woff_b + featT_b;

  const size_t idx_b = (size_t)BB * SS * NS * sizeof(int);       // fallback

  if (ws_size >= grid_need) {
    char* w = (char*)d_ws;
    float4* pts   = (float4*)w;                      w += pts_b;
    int*    off   = (int*)w;                         w += off_b;
    int*    hist  = (int*)w;                         w += hist_b;
    int*    woff  = (int*)w;                         w += woff_b;
    float*  featT = (float*)w;
    hipMemsetAsync(hist, 0, hist_b, stream);
    qg_tr_hist<<<512, 256, 0, stream>>>(xyz, feat, featT, hist);
    qg_scan<<<BB, 256, 0, stream>>>(hist, off, woff);
    qg_scatter<<<(BB * NN) / 256, 256, 0, stream>>>(xyz, woff, pts);
    qg_main<<<BB * (SS / SCH), GT, 0, stream>>>(xyz, nxyz, pts, off, featT,
                                                fps, out);
  } else if (ws_size >= idx_b + featT_b) {
    int* wsidx = (int*)d_ws;
    float* featT = (float*)((char*)d_ws + idx_b);
    qg_prep<<<3072, 256, 0, stream>>>(xyz, nxyz, feat, wsidx, featT);
    qg_gather2<<<BB * (SS / SCH), GT, 0, stream>>>(xyz, nxyz, featT, fps,
                                                   wsidx, out);
  } else if (ws_size >= idx_b) {
    int* wsidx = (int*)d_ws;
    qg_ballq<<<(BB * SS) / 4, 256, 0, stream>>>(xyz, nxyz, wsidx);
    unsigned tot = (unsigned)BB * OC * SS * KK;
    qg_gather<<<(tot + 255u) / 256u, 256, 0, stream>>>(xyz, nxyz, feat, fps,
                                                       wsidx, out);
  } else {
    qg_fused<<<(BB * SS) / 4, 256, 0, stream>>>(xyz, nxyz, feat, fps, out);
  }
}

// Round 8
// 55.259 us; speedup vs baseline: 1.3966x; 1.0585x over previous
//
#include <hip/hip_runtime.h>

#define BB 4
#define NN 16384
#define SS 2048
#define CC 64
#define NS 32
#define KK 33   // NS + 1 (fps_idx prepended)
#define OC 70   // 3 raw xyz + 3 centered xyz + 64 features
#define SCH 4   // s-chunk per main block
#define GT 512  // gather/main block threads
#define NC 10
#define NCELL 1000
#define HCAP 224         // per-wave hit buffer cap (avg hits ~62)
#define RPAD 0.100001f   // cell-range pad (covers fp rounding of d2 test)

// --- prevent fma contraction so d2 matches the np/jax fp32 reference ---
__device__ __forceinline__ float sq_nofma(float v) {
  float r = v * v;
  asm volatile("" : "+v"(r));
  return r;
}

__device__ __forceinline__ int cell1(float x) {
  int c = (int)(x * 10.0f);
  return c < 0 ? 0 : (c > 9 ? 9 : c);
}
__device__ __forceinline__ int cell3(float x, float y, float z) {
  return (cell1(z) * NC + cell1(y)) * NC + cell1(x);
}

// ---------------- legacy wave ball-query (fallback + overflow path) -------
__device__ __forceinline__ void ball_query_wave(
    const float* __restrict__ xb, float qx, float qy, float qz, int lane,
    int* out) {
  const float R2 = 0.01f;
  int cnt = 0;
  int firstIdx = 0;
  for (int base = 0; base < NN; base += 256) {
    float px[4], py[4], pz[4];
#pragma unroll
    for (int j = 0; j < 4; ++j) {
      int n = base + j * 64 + lane;
      const float* p = xb + n * 3;
      px[j] = p[0]; py[j] = p[1]; pz[j] = p[2];
    }
#pragma unroll
    for (int j = 0; j < 4; ++j) {
      float dx = px[j] - qx, dy = py[j] - qy, dz = pz[j] - qz;
      float d2 = sq_nofma(dx) + sq_nofma(dy);
      asm volatile("" : "+v"(d2));
      d2 = d2 + sq_nofma(dz);
      bool m = d2 < R2;
      unsigned long long bal = __ballot(m);
      if (cnt == 0 && bal) firstIdx = base + j * 64 + __builtin_ctzll(bal);
      int pos = cnt + (int)__popcll(bal & ((1ull << lane) - 1ull));
      if (m && pos < NS) out[pos] = base + j * 64 + lane;
      cnt += (int)__popcll(bal);
    }
    if (cnt >= NS) break;
  }
  if (cnt < NS) {
    int pad = (cnt == 0) ? 0 : firstIdx;
    if (lane >= cnt && lane < NS) out[lane] = pad;
  }
}

// ---------------- K1: float4 transpose + privatized LDS histogram ---------
// 512 blocks: bid -> (b, n0 in 256-steps, cc in {0,1} = 32-channel half).
// cc==0 blocks histogram their 256 points in LDS and WRITE a partial row
// (no global atomics, no pre-zeroed global buffer needed).
__global__ __launch_bounds__(256) void qg_tr_hist2(
    const float* __restrict__ xyz, const float* __restrict__ feat,
    float* __restrict__ featT, int* __restrict__ partial) {
  __shared__ float tile[32 * 260];  // 32 rows, stride 260 (pad kills conflicts)
  __shared__ int h[1024];
  const int bid = (int)blockIdx.x;
  const int tid = (int)threadIdx.x;
  const int b = bid >> 7;
  const int rest = bid & 127;
  const int n0 = (rest >> 1) << 8;  // 0,256,...,16128
  const int cc = rest & 1;
  const int c0 = cc << 5;  // 0 or 32
  const int wv = tid >> 6, lane = tid & 63;

  if (cc == 0) {  // LDS histogram of this block's 256 points
#pragma unroll
    for (int c = tid; c < 1024; c += 256) h[c] = 0;
    __syncthreads();
    const float* p = xyz + ((size_t)b * NN + n0 + tid) * 3;
    atomicAdd(&h[cell3(p[0], p[1], p[2])], 1);
  }

  const float* fb = feat + ((size_t)b * CC + c0) * NN + n0;
#pragma unroll
  for (int rr = 0; rr < 8; ++rr) {
    int c = rr * 4 + wv;  // 0..31
    float4 v = *(const float4*)(fb + (size_t)c * NN + 4 * lane);
    *(float4*)&tile[c * 260 + 4 * lane] = v;
  }
  __syncthreads();  // covers both tile writes and h atomics
  const int c4 = lane & 7, m = lane >> 3;
  float4* oT = (float4*)(featT + ((size_t)b * NN + n0) * CC);
#pragma unroll
  for (int it = 0; it < 8; ++it) {
    int n = it * 32 + wv * 8 + m;  // 0..255
    float4 v;
    v.x = tile[(4 * c4 + 0) * 260 + n];
    v.y = tile[(4 * c4 + 1) * 260 + n];
    v.z = tile[(4 * c4 + 2) * 260 + n];
    v.w = tile[(4 * c4 + 3) * 260 + n];
    oT[(size_t)n * (CC / 4) + (c0 >> 2) + c4] = v;
  }

  if (cc == 0) {  // publish partial histogram (coalesced writes)
    const int j = rest >> 1;  // 0..63? no: 0..127 step covers even rest only
    int* pr = partial + (((size_t)b * 128 + j) << 10);
#pragma unroll
    for (int c = tid; c < 1024; c += 256) pr[c] = h[c];
  }
}

// ---------------- K1b: sum partials + per-batch exclusive scan ------------
__global__ __launch_bounds__(256) void qg_scan2(
    const int* __restrict__ partial, int* __restrict__ off,
    int* __restrict__ woff) {
  __shared__ int sc[256];
  const int b = (int)blockIdx.x;
  const int tid = (int)threadIdx.x;
  int l0 = 0, l1 = 0, l2 = 0, l3 = 0;
  // sum over the 64 partial rows of this batch (j = 0..63: rest even only
  // => j index space is 0..127 but only even rest produce cc==0; mapping
  // below uses j = rest>>1 in [0,64)). 64 rows x 1024 cells.
  for (int j = 0; j < 64; j += 4) {
#pragma unroll
    for (int jj = 0; jj < 4; ++jj) {
      const int4 v = ((const int4*)(partial + (((size_t)b * 128 + j + jj) << 10)))[tid];
      l0 += v.x; l1 += v.y; l2 += v.z; l3 += v.w;
    }
  }
  int base = tid * 4;
  int s1 = l0, s2 = l0 + l1, s3 = l0 + l1 + l2, tot = s3 + l3;
  sc[tid] = tot;
  __syncthreads();
  for (int d = 1; d < 256; d <<= 1) {
    int v = (tid >= d) ? sc[tid - d] : 0;
    __syncthreads();
    sc[tid] += v;
    __syncthreads();
  }
  int ex = sc[tid] - tot;
  int* offb = off + b * (NCELL + 1);
  int* woffb = woff + b * NCELL;
  if (base + 0 < NCELL) { offb[base + 0] = ex;      woffb[base + 0] = ex; }
  if (base + 1 < NCELL) { offb[base + 1] = ex + s1; woffb[base + 1] = ex + s1; }
  if (base + 2 < NCELL) { offb[base + 2] = ex + s2; woffb[base + 2] = ex + s2; }
  if (base + 3 < NCELL) { offb[base + 3] = ex + s3; woffb[base + 3] = ex + s3; }
  if (tid == 0) offb[NCELL] = NN;
}

// ---------------- K2: counting-sort scatter (verified R3/R5/R6/R7) --------
__global__ __launch_bounds__(256) void qg_scatter(
    const float* __restrict__ xyz, int* __restrict__ woff,
    float4* __restrict__ pts) {
  int i = (int)(blockIdx.x * 256u + threadIdx.x);  // 0..65535
  int b = i >> 14, n = i & (NN - 1);
  const float* p = xyz + ((size_t)b * NN + n) * 3;
  float x = p[0], y = p[1], z = p[2];
  int cell = cell3(x, y, z);
  int pos = atomicAdd(&woff[b * NCELL + cell], 1);
  pts[(b << 14) + pos] = make_float4(x, y, z, __int_as_float(n));
}

// ---------------- K3: fused grid ball-query + gather (R7-verified) --------
__global__ __launch_bounds__(GT) void qg_main(
    const float* __restrict__ xyz, const float* __restrict__ nxyz,
    const float4* __restrict__ pts, const int* __restrict__ off,
    const float* __restrict__ featT, const int* __restrict__ fps,
    float* __restrict__ out) {
  __shared__ float sf[CC][SCH * KK + 1];  // [64][133] padded: 0 bank conflicts
  __shared__ int sidx[SCH * KK];          // 132
  __shared__ int hitbuf[SCH][HCAP];
  __shared__ int hcnt_s[SCH];
  const int tid = (int)threadIdx.x;
  const int blk = (int)blockIdx.x;  // 0..2047
  const int b = blk >> 9;
  const int s0 = (blk & 511) * SCH;
  const int wv = tid >> 6, lane = tid & 63;

  // ---- phase 1: ball query (waves 0..3, one query each) ----
  if (wv < SCH) {
    const int q = b * SS + s0 + wv;
    const float R2 = 0.01f;
    float qx = nxyz[q * 3 + 0];
    float qy = nxyz[q * 3 + 1];
    float qz = nxyz[q * 3 + 2];
    int* hb = hitbuf[wv];
    int* qout = &sidx[wv * KK];
    if (lane == 0) hcnt_s[wv] = 0;
    asm volatile("s_waitcnt lgkmcnt(0)" ::: "memory");

    int lox = max(0, (int)floorf((qx - RPAD) * 10.f));
    int hix = min(9, (int)floorf((qx + RPAD) * 10.f));
    int loy = max(0, (int)floorf((qy - RPAD) * 10.f));
    int hiy = min(9, (int)floorf((qy + RPAD) * 10.f));
    int loz = max(0, (int)floorf((qz - RPAD) * 10.f));
    int hiz = min(9, (int)floorf((qz + RPAD) * 10.f));

    // hoist span bounds: lane i in [0,9) owns span (loz+i/3, loy+i%3)
    const int* offb = off + b * (NCELL + 1);
    int start_l = 0, end_l = 0;
    {
      int cz = loz + lane / 3, cy = loy + lane % 3;
      if (lane < 9 && cz <= hiz && cy <= hiy) {
        int row = (cz * NC + cy) * NC;
        start_l = offb[row + lox];
        end_l = offb[row + hix + 1];
      }
    }
    const float4* pb = pts + ((size_t)b << 14);
    // dependence-free candidate loop: loads pipeline, no per-iter ballot
    for (int sp = 0; sp < 9; ++sp) {
      int start = __shfl(start_l, sp, 64);
      int end = __shfl(end_l, sp, 64);
      for (int p0 = start; p0 < end; p0 += 64) {
        int ii = p0 + lane;
        bool valid = ii < end;
        float4 v = pb[valid ? ii : (end - 1)];
        float dx = v.x - qx, dy = v.y - qy, dz = v.z - qz;
        float d2 = sq_nofma(dx) + sq_nofma(dy);
        asm volatile("" : "+v"(d2));
        d2 = d2 + sq_nofma(dz);
        if (valid && d2 < R2) {
          int pos = atomicAdd(&hcnt_s[wv], 1);
          if (pos < HCAP) hb[pos] = __float_as_int(v.w);
        }
      }
    }
    asm volatile("s_waitcnt lgkmcnt(0)" ::: "memory");
    const int M = hcnt_s[wv];
    if (M > HCAP) {
      // safety net: exact legacy linear scan (prob ~0 on this data)
      ball_query_wave(xyz + (size_t)b * NN * 3, qx, qy, qz, lane, qout + 1);
    } else {
      // rank by original index = output position (order-independent)
      int minv = 0x7fffffff;
      for (int i = lane; i < M; i += 64) {
        int hh = hb[i];
        minv = min(minv, hh);
        int rank = 0;
        for (int j = 0; j < M; ++j) rank += (hb[j] < hh) ? 1 : 0;
        if (rank < NS) qout[1 + rank] = hh;
      }
      if (M < NS) {
#pragma unroll
        for (int d = 1; d < 64; d <<= 1)
          minv = min(minv, __shfl_xor(minv, d, 64));
        int pad = (M == 0) ? 0 : minv;
        if (lane >= M && lane < NS) qout[1 + lane] = pad;
      }
    }
    if (lane == 0) qout[0] = fps[q];
  }
  __syncthreads();

  // ---- phase 2: gather features -> padded LDS (all 512 threads) ----
  const size_t cstr = (size_t)SS * KK;
  const float4* fT4 = (const float4*)(featT + (size_t)b * NN * CC);
  int e = tid & 15;
  for (int pp = tid >> 4; pp < SCH * KK; pp += GT / 16) {
    int n = sidx[pp];
    float4 v = fT4[(size_t)n * (CC / 4) + e];
    sf[4 * e + 0][pp] = v.x;
    sf[4 * e + 1][pp] = v.y;
    sf[4 * e + 2][pp] = v.z;
    sf[4 * e + 3][pp] = v.w;
  }

  // xyz channels (0..5): direct coalesced scalar writes
  if (tid < SCH * KK) {
    int s4 = tid / KK;
    int n = sidx[tid];
    const float* p = xyz + ((size_t)b * NN + n) * 3;
    float x = p[0], y = p[1], z = p[2];
    int q = b * SS + s0 + s4;
    float cx = nxyz[q * 3 + 0], cy = nxyz[q * 3 + 1], cz = nxyz[q * 3 + 2];
    size_t obase = ((size_t)(b * OC) * SS + s0) * KK + tid;
    out[obase + 0 * cstr] = x;
    out[obase + 1 * cstr] = y;
    out[obase + 2 * cstr] = z;
    out[obase + 3 * cstr] = x - cx;
    out[obase + 4 * cstr] = y - cy;
    out[obase + 5 * cstr] = z - cz;
  }
  __syncthreads();

  // ---- phase 3: feature channel rows, linear scalar stores ----
  size_t fbase = ((size_t)(b * OC + 6) * SS + s0) * KK;
  for (int idx = tid; idx < CC * SCH * KK; idx += GT) {
    int c = idx / (SCH * KK);
    int j = idx - c * (SCH * KK);
    out[fbase + (size_t)c * cstr + j] = sf[c][j];
  }
}

// ---------------- legacy fallback kernels (small-ws paths) ----------------
__global__ __launch_bounds__(256) void qg_prep(
    const float* __restrict__ xyz, const float* __restrict__ nxyz,
    const float* __restrict__ feat, int* __restrict__ wsidx,
    float* __restrict__ featT) {
  __shared__ float tile[64][65];
  int bid = (int)blockIdx.x;
  int r3 = bid % 3;
  if (r3 < 2) {
    int lane = (int)(threadIdx.x & 63);
    int q = ((bid / 3) * 2 + r3) * 4 + (int)(threadIdx.x >> 6);
    int b = q >> 11;
    const float* xb = xyz + (size_t)b * NN * 3;
    ball_query_wave(xb, nxyz[q * 3], nxyz[q * 3 + 1], nxyz[q * 3 + 2], lane,
                    wsidx + (size_t)q * NS);
  } else {
    int tb = bid / 3;
    int b = tb >> 8;
    int n0 = (tb & 255) << 6;
    int tx = (int)(threadIdx.x & 63);
    int ty = (int)(threadIdx.x >> 6);
    const float* fb = feat + (size_t)b * CC * NN + n0;
#pragma unroll
    for (int r = 0; r < 16; ++r) {
      int c = r * 4 + ty;
      tile[c][tx] = fb[(size_t)c * NN + tx];
    }
    __syncthreads();
    float* ob = featT + ((size_t)b * NN + n0) * CC;
#pragma unroll
    for (int r = 0; r < 16; ++r) {
      int n = r * 4 + ty;
      ob[(size_t)n * CC + tx] = tile[tx][n];
    }
  }
}

__global__ __launch_bounds__(GT) void qg_gather2(
    const float* __restrict__ xyz, const float* __restrict__ nxyz,
    const float* __restrict__ featT, const int* __restrict__ fps,
    const int* __restrict__ wsidx, float* __restrict__ out) {
  __shared__ float sf[CC][SCH * KK + 1];
  __shared__ int sidx[SCH * KK];
  const int tid = (int)threadIdx.x;
  const int blk = (int)blockIdx.x;
  const int b = blk >> 9;
  const int s0 = (blk & 511) * SCH;
  const size_t cstr = (size_t)SS * KK;

  if (tid < SCH * KK) {
    int s4 = tid / KK, k = tid - s4 * KK;
    int q = b * SS + s0 + s4;
    sidx[tid] = (k == 0) ? fps[q] : wsidx[(size_t)q * NS + (k - 1)];
  }
  __syncthreads();

  const float4* fT4 = (const float4*)(featT + (size_t)b * NN * CC);
  int e = tid & 15;
  for (int pp = tid >> 4; pp < SCH * KK; pp += GT / 16) {
    int n = sidx[pp];
    float4 v = fT4[(size_t)n * (CC / 4) + e];
    sf[4 * e + 0][pp] = v.x;
    sf[4 * e + 1][pp] = v.y;
    sf[4 * e + 2][pp] = v.z;
    sf[4 * e + 3][pp] = v.w;
  }

  if (tid < SCH * KK) {
    int s4 = tid / KK;
    int n = sidx[tid];
    const float* p = xyz + ((size_t)b * NN + n) * 3;
    float x = p[0], y = p[1], z = p[2];
    int q = b * SS + s0 + s4;
    float cx = nxyz[q * 3 + 0], cy = nxyz[q * 3 + 1], cz = nxyz[q * 3 + 2];
    size_t obase = ((size_t)(b * OC) * SS + s0) * KK + tid;
    out[obase + 0 * cstr] = x;
    out[obase + 1 * cstr] = y;
    out[obase + 2 * cstr] = z;
    out[obase + 3 * cstr] = x - cx;
    out[obase + 4 * cstr] = y - cy;
    out[obase + 5 * cstr] = z - cz;
  }
  __syncthreads();

  size_t fbase = ((size_t)(b * OC + 6) * SS + s0) * KK;
  for (int idx = tid; idx < CC * SCH * KK; idx += GT) {
    int c = idx / (SCH * KK);
    int j = idx - c * (SCH * KK);
    out[fbase + (size_t)c * cstr + j] = sf[c][j];
  }
}

__global__ __launch_bounds__(256) void qg_ballq(
    const float* __restrict__ xyz, const float* __restrict__ nxyz,
    int* __restrict__ wsidx) {
  int q = (int)((blockIdx.x * blockDim.x + threadIdx.x) >> 6);
  int lane = (int)(threadIdx.x & 63);
  int b = q / SS;
  const float* xb = xyz + (size_t)b * NN * 3;
  ball_query_wave(xb, nxyz[q * 3], nxyz[q * 3 + 1], nxyz[q * 3 + 2], lane,
                  wsidx + (size_t)q * NS);
}

__global__ __launch_bounds__(256) void qg_gather(
    const float* __restrict__ xyz, const float* __restrict__ nxyz,
    const float* __restrict__ feat, const int* __restrict__ fps,
    const int* __restrict__ wsidx, float* __restrict__ out) {
  unsigned t = blockIdx.x * 256u + threadIdx.x;
  const unsigned TOT = (unsigned)BB * OC * SS * KK;
  if (t >= TOT) return;
  unsigned k = t % KK;
  unsigned r = t / KK;
  unsigned s = r % SS;
  r /= SS;
  unsigned c = r % OC;
  unsigned b = r / OC;
  unsigned q = b * SS + s;
  int n = (k == 0) ? fps[q] : wsidx[(size_t)q * NS + (k - 1)];
  float v;
  if (c < 6) {
    unsigned cc = (c < 3) ? c : c - 3;
    v = xyz[((size_t)b * NN + (unsigned)n) * 3 + cc];
    if (c >= 3) v -= nxyz[q * 3 + cc];
  } else {
    v = feat[((size_t)b * CC + (c - 6)) * NN + (unsigned)n];
  }
  out[t] = v;
}

__global__ __launch_bounds__(256) void qg_fused(
    const float* __restrict__ xyz, const float* __restrict__ nxyz,
    const float* __restrict__ feat, const int* __restrict__ fps,
    float* __restrict__ out) {
  __shared__ int sidx[4][KK];
  int wv = (int)(threadIdx.x >> 6), lane = (int)(threadIdx.x & 63);
  int q = (int)blockIdx.x * 4 + wv;
  int b = q / SS, s = q % SS;
  const float* xb = xyz + (size_t)b * NN * 3;
  ball_query_wave(xb, nxyz[q * 3], nxyz[q * 3 + 1], nxyz[q * 3 + 2], lane,
                  &sidx[wv][1]);
  if (lane == 0) sidx[wv][0] = fps[q];
  __syncthreads();
  for (int f = lane; f < OC * KK; f += 64) {
    int c = f / KK, k = f - c * KK;
    int n = sidx[wv][k];
    float v;
    if (c < 6) {
      int cc = (c < 3) ? c : c - 3;
      v = xb[n * 3 + cc];
      if (c >= 3) v -= nxyz[q * 3 + cc];
    } else {
      v = feat[((size_t)b * CC + (c - 6)) * NN + n];
    }
    out[((size_t)((size_t)b * OC + c) * SS + s) * KK + k] = v;
  }
}

extern "C" void kernel_launch(void* const* d_in, const int* in_sizes, int n_in,
                              void* d_out, int out_size, void* d_ws, size_t ws_size,
                              hipStream_t stream) {
  const float* xyz  = (const float*)d_in[0];   // (B, N, 3)
  const float* nxyz = (const float*)d_in[1];   // (B, S, 3)
  const float* feat = (const float*)d_in[2];   // (B, C, N)
  const int*   fps  = (const int*)d_in[3];     // (B, S)
  float* out = (float*)d_out;                  // (B, 70, S, 33)

  const size_t pts_b     = (size_t)BB * NN * sizeof(float4);     // 1 MiB
  const size_t off_b     = 16384;
  const size_t partial_b = (size_t)BB * 128 * 1024 * sizeof(int);// 2 MiB
  const size_t woff_b    = 16384;
  const size_t featT_b   = (size_t)BB * NN * CC * sizeof(float); // 16.8 MB
  const size_t grid_need = pts_b + off_b + partial_b + woff_b + featT_b;

  const size_t idx_b = (size_t)BB * SS * NS * sizeof(int);       // fallback

  if (ws_size >= grid_need) {
    char* w = (char*)d_ws;
    float4* pts     = (float4*)w;                    w += pts_b;
    int*    off     = (int*)w;                       w += off_b;
    int*    partial = (int*)w;                       w += partial_b;
    int*    woff    = (int*)w;                       w += woff_b;
    float*  featT   = (float*)w;
    qg_tr_hist2<<<512, 256, 0, stream>>>(xyz, feat, featT, partial);
    qg_scan2<<<BB, 256, 0, stream>>>(partial, off, woff);
    qg_scatter<<<(BB * NN) / 256, 256, 0, stream>>>(xyz, woff, pts);
    qg_main<<<BB * (SS / SCH), GT, 0, stream>>>(xyz, nxyz, pts, off, featT,
                                                fps, out);
  } else if (ws_size >= idx_b + featT_b) {
    int* wsidx = (int*)d_ws;
    float* featT = (float*)((char*)d_ws + idx_b);
    qg_prep<<<3072, 256, 0, stream>>>(xyz, nxyz, feat, wsidx, featT);
    qg_gather2<<<BB * (SS / SCH), GT, 0, stream>>>(xyz, nxyz, featT, fps,
                                                   wsidx, out);
  } else if (ws_size >= idx_b) {
    int* wsidx = (int*)d_ws;
    qg_ballq<<<(BB * SS) / 4, 256, 0, stream>>>(xyz, nxyz, wsidx);
    unsigned tot = (unsigned)BB * OC * SS * KK;
    qg_gather<<<(tot + 255u) / 256u, 256, 0, stream>>>(xyz, nxyz, feat, fps,
                                                       wsidx, out);
  } else {
    qg_fused<<<(BB * SS) / 4, 256, 0, stream>>>(xyz, nxyz, feat, fps, out);
  }
}